// Round 8
// baseline (2060.044 us; speedup 1.0000x reference)
//
#include <hip/hip_runtime.h>
#include <stdint.h>
#include <math.h>

#define BROWS 16384

typedef _Float16 h8 __attribute__((ext_vector_type(8)));
typedef _Float16 h4 __attribute__((ext_vector_type(4)));
typedef __bf16   b8 __attribute__((ext_vector_type(8)));
typedef __bf16   b4 __attribute__((ext_vector_type(4)));
typedef float    f4 __attribute__((ext_vector_type(4)));
typedef float    f16v __attribute__((ext_vector_type(16)));

typedef __attribute__((address_space(3))) char       lds_char;
typedef __attribute__((address_space(1))) const char gbl_char;

// async global->LDS, 16B per lane; LDS dest = wave-uniform base + lane*16
// (global SOURCE address is per-lane -> usable as gather AND as pre-swizzle)
__device__ __forceinline__ void gload16(const void* g, void* l) {
  __builtin_amdgcn_global_load_lds((const gbl_char*)(uintptr_t)g,
                                   (lds_char*)(uintptr_t)l, 16, 0, 0);
}

// BK=64 tile: [128 rows][64 halfs] = 16KB/plane, row stride 128B.
// LDS(row, cb) holds global colblock cb^(row&7)  [staged via pre-swizzled
// per-lane global source colbyte ((l&7)^(l>>3))*16, linear LDS dest].
// 32x32x16 fragment: lane reads row (l&31), k = ks*16 + (l>>5)*8 + j
//   -> LDS colblock ((ks*2 + (l>>5)) ^ (l&7)), conflict-free (8 words/bank).
// C/D map (32x32): col=lane&31, row=(reg&3)+8*(reg>>2)+4*(lane>>5).

// ---------------------------------------------------------------------------
// fp16 2-term split GEMM:  C = A @ W^T (+epilogue), A = Ah + Al/2048,
// W = Wh + Wl/2048, row-major, K contiguous. blockIdx.z selects second
// weight set / bias and offsets A,C by zoff (merged p1+p2 launch).
// EPI 0: y += v0[col]; write split planes Ch/Cl          (p1, p2)
// EPI 1: y = relu(y*v0[col] + v1[col]); write Ch/Cl      (m1, m2)
// EPI 2: Cf = y + v0[col]  (f32)                          (m3)
// ---------------------------------------------------------------------------
template<int EPI>
__global__ __launch_bounds__(256, 2)
void gemm_split(const _Float16* __restrict__ Ah, const _Float16* __restrict__ Al,
                const _Float16* __restrict__ Wh, const _Float16* __restrict__ Wl,
                const _Float16* __restrict__ WhB, const _Float16* __restrict__ WlB,
                const int lda, const int ldw, const int K,
                _Float16* __restrict__ Ch, _Float16* __restrict__ Cl,
                float* __restrict__ Cf, const int ldc,
                const float* __restrict__ v0, const float* __restrict__ v1,
                const float* __restrict__ v0B, const int zoff)
{
  __shared__ char smem[65536];
  char* const sAh = smem;
  char* const sAl = smem + 16384;
  char* const sWh = smem + 32768;
  char* const sWl = smem + 49152;

  if (blockIdx.z) {               // wave-uniform select (p2 of the merged pair)
    Wh = WhB; Wl = WlB; v0 = v0B;
    Ah += zoff; Al += zoff; Ch += zoff; Cl += zoff;
  }

  const int tid  = threadIdx.x;
  const int wid  = tid >> 6, lane = tid & 63;
  const int bm = blockIdx.x, bn = blockIdx.y;
  const int wr = wid >> 1, wc = wid & 1;          // 2x2 waves, 64x64 each
  const int sr  = lane >> 3;                      // staging row-in-8
  const int scb = ((lane & 7) ^ sr) * 16;         // pre-swizzled source colbyte
  const int fb  = lane & 31;                      // fragment row/col (32-wide)
  const int fx  = lane >> 5;                      // k-half select
  const int s7  = lane & 7;

  f16v accA[2][2] = {};
  f16v accB[2][2] = {};

  const size_t arow0 = (size_t)bm * 128;
  const size_t wrow0 = (size_t)bn * 128;

  for (int k0 = 0; k0 < K; k0 += 64) {
    __syncthreads();
#pragma unroll
    for (int i = 0; i < 4; ++i) {
      const int rb = wid * 32 + i * 8;
      const size_t ga = (arow0 + rb + sr) * (size_t)lda + k0;
      const size_t gw = (wrow0 + rb + sr) * (size_t)ldw + k0;
      const int lo = rb * 128;                    // wave-uniform LDS base
      gload16((const char*)(Ah + ga) + scb, sAh + lo);
      gload16((const char*)(Al + ga) + scb, sAl + lo);
      gload16((const char*)(Wh + gw) + scb, sWh + lo);
      gload16((const char*)(Wl + gw) + scb, sWl + lo);
    }
    __syncthreads();

#pragma unroll
    for (int ks = 0; ks < 4; ++ks) {
      const int sw = ((ks * 2 + fx) ^ s7) * 16;
      h8 ah[2], al[2], bh[2], bl[2];
#pragma unroll
      for (int mi = 0; mi < 2; ++mi) {
        const int r = (wr * 64 + mi * 32 + fb) * 128 + sw;
        ah[mi] = *(const h8*)(sAh + r);
        al[mi] = *(const h8*)(sAl + r);
      }
#pragma unroll
      for (int ni = 0; ni < 2; ++ni) {
        const int r = (wc * 64 + ni * 32 + fb) * 128 + sw;
        bh[ni] = *(const h8*)(sWh + r);
        bl[ni] = *(const h8*)(sWl + r);
      }
#pragma unroll
      for (int mi = 0; mi < 2; ++mi)
#pragma unroll
        for (int ni = 0; ni < 2; ++ni) {
          accA[mi][ni] = __builtin_amdgcn_mfma_f32_32x32x16_f16(ah[mi], bh[ni], accA[mi][ni], 0, 0, 0);
          accB[mi][ni] = __builtin_amdgcn_mfma_f32_32x32x16_f16(ah[mi], bl[ni], accB[mi][ni], 0, 0, 0);
          accB[mi][ni] = __builtin_amdgcn_mfma_f32_32x32x16_f16(al[mi], bh[ni], accB[mi][ni], 0, 0, 0);
        }
    }
  }

#pragma unroll
  for (int mi = 0; mi < 2; ++mi)
#pragma unroll
    for (int ni = 0; ni < 2; ++ni) {
      const int gcol = bn * 128 + wc * 64 + ni * 32 + fb;
      const float a0 = v0[gcol];
      const float a1 = (EPI == 1) ? v1[gcol] : 0.f;
#pragma unroll
      for (int r = 0; r < 16; ++r) {
        const int row32 = (r & 3) + 8 * (r >> 2) + 4 * fx;
        const size_t grow = arow0 + wr * 64 + mi * 32 + row32;
        float y = accA[mi][ni][r] + accB[mi][ni][r] * (1.f / 2048.f);
        const size_t off = grow * (size_t)ldc + gcol;
        if constexpr (EPI == 0) {
          y += a0;
          const _Float16 hh = (_Float16)y;
          Ch[off] = hh;
          Cl[off] = (_Float16)((y - (float)hh) * 2048.f);
        } else if constexpr (EPI == 1) {
          y = fmaxf(fmaf(y, a0, a1), 0.f);
          const _Float16 hh = (_Float16)y;
          Ch[off] = hh;
          Cl[off] = (_Float16)((y - (float)hh) * 2048.f);
        } else {
          Cf[off] = y + a0;
        }
      }
    }
}

// ---------------------------------------------------------------------------
// bf16 GEMM for the fus layer: Cf = (A @ W^T)*v0[col] + v1[col]   (BK=64)
// ---------------------------------------------------------------------------
__global__ __launch_bounds__(256, 2)
void gemm_fus(const __bf16* __restrict__ A, const __bf16* __restrict__ W,
              const int lda, const int ldw, const int K,
              float* __restrict__ Cf, const int ldc,
              const float* __restrict__ v0, const float* __restrict__ v1)
{
  __shared__ char smem[32768];
  char* const sA = smem;
  char* const sW = smem + 16384;

  const int tid  = threadIdx.x;
  const int wid  = tid >> 6, lane = tid & 63;
  const int bm = blockIdx.x, bn = blockIdx.y;
  const int wr = wid >> 1, wc = wid & 1;
  const int sr  = lane >> 3;
  const int scb = ((lane & 7) ^ sr) * 16;
  const int fb  = lane & 31;
  const int fx  = lane >> 5;
  const int s7  = lane & 7;

  f16v acc[2][2] = {};

  const size_t arow0 = (size_t)bm * 128;
  const size_t wrow0 = (size_t)bn * 128;

  for (int k0 = 0; k0 < K; k0 += 64) {
    __syncthreads();
#pragma unroll
    for (int i = 0; i < 4; ++i) {
      const int rb = wid * 32 + i * 8;
      const size_t ga = (arow0 + rb + sr) * (size_t)lda + k0;
      const size_t gw = (wrow0 + rb + sr) * (size_t)ldw + k0;
      const int lo = rb * 128;
      gload16((const char*)(A + ga) + scb, sA + lo);
      gload16((const char*)(W + gw) + scb, sW + lo);
    }
    __syncthreads();

#pragma unroll
    for (int ks = 0; ks < 4; ++ks) {
      const int sw = ((ks * 2 + fx) ^ s7) * 16;
      b8 av[2], bv[2];
#pragma unroll
      for (int mi = 0; mi < 2; ++mi)
        av[mi] = *(const b8*)(sA + (wr * 64 + mi * 32 + fb) * 128 + sw);
#pragma unroll
      for (int ni = 0; ni < 2; ++ni)
        bv[ni] = *(const b8*)(sW + (wc * 64 + ni * 32 + fb) * 128 + sw);
#pragma unroll
      for (int mi = 0; mi < 2; ++mi)
#pragma unroll
        for (int ni = 0; ni < 2; ++ni)
          acc[mi][ni] = __builtin_amdgcn_mfma_f32_32x32x16_bf16(av[mi], bv[ni], acc[mi][ni], 0, 0, 0);
    }
  }

#pragma unroll
  for (int mi = 0; mi < 2; ++mi)
#pragma unroll
    for (int ni = 0; ni < 2; ++ni) {
      const int gcol = bn * 128 + wc * 64 + ni * 32 + fb;
#pragma unroll
      for (int r = 0; r < 16; ++r) {
        const int row32 = (r & 3) + 8 * (r >> 2) + 4 * fx;
        const size_t grow = arow0 + wr * 64 + mi * 32 + row32;
        Cf[grow * (size_t)ldc + gcol] = fmaf(acc[mi][ni][r], v0[gcol], v1[gcol]);
      }
    }
}

// ---------------------------------------------------------------------------
// gathered per-(half,rank) expert GEMM (BK=64, 32x32 MFMA). Block bx: 128
// worklist rows, all expert blkexp[bx]; by = 128-col tile. A rows gathered
// via per-lane global_load_lds source addresses (pre-swizzled cols).
// PASS 0 (rank 0): ACC[row][col]  = w * ( (A[row] @ We^T)[col] + be[col] )
// PASS 1 (rank 1): BFBh[row][col] = bf16( ACC[row][col] + w * (... ) )
// ---------------------------------------------------------------------------
template<int PASS>
__global__ __launch_bounds__(256, 2)
void gemm_moe(const __bf16* __restrict__ A,      // BFA + h*1024, lda 2048
              const __bf16* __restrict__ Wall,   // 8 x (1024x1024) bf16
              const int* __restrict__ lrow, const float* __restrict__ lw,
              const int* __restrict__ blkexp,
              const float* __restrict__ eb,      // ex_b (8x1024)
              float* __restrict__ ACC,           // CM x 1024 f32
              __bf16* __restrict__ BFBh)         // BFB + h*1024, ld 2048
{
  const int bx = blockIdx.x, by = blockIdx.y;
  const int e = blkexp[bx];
  if (e < 0) return;                              // fully-pad block

  __shared__ char smem[32768];
  __shared__ int   slrow[128];
  __shared__ float slw[128];
  char* const sA = smem;
  char* const sW = smem + 16384;

  const int tid  = threadIdx.x;
  const int wid  = tid >> 6, lane = tid & 63;
  if (tid < 128) { slrow[tid] = lrow[bx * 128 + tid]; slw[tid] = lw[bx * 128 + tid]; }
  __syncthreads();

  const __bf16* W = Wall + (size_t)e * 1048576 + (size_t)by * 131072;

  const int wr = wid >> 1, wc = wid & 1;
  const int sr  = lane >> 3;
  const int scb = ((lane & 7) ^ sr) * 16;
  const int fb  = lane & 31;
  const int fx  = lane >> 5;
  const int s7  = lane & 7;

  // per-lane gathered A base pointers (4 staging loads per wave)
  const char* abase[4];
#pragma unroll
  for (int i = 0; i < 4; ++i) {
    int s = slrow[wid * 32 + i * 8 + sr];
    if (s < 0) s = 0;
    abase[i] = (const char*)(A + (size_t)s * 2048) + scb;
  }

  f16v acc[2][2] = {};

  for (int k0 = 0; k0 < 1024; k0 += 64) {
    __syncthreads();
#pragma unroll
    for (int i = 0; i < 4; ++i) {
      const int rb = wid * 32 + i * 8;
      const int lo = rb * 128;
      gload16(abase[i] + (size_t)k0 * 2, sA + lo);
      gload16((const char*)(W + (size_t)(rb + sr) * 1024 + k0) + scb, sW + lo);
    }
    __syncthreads();

#pragma unroll
    for (int ks = 0; ks < 4; ++ks) {
      const int sw = ((ks * 2 + fx) ^ s7) * 16;
      b8 av[2], bv[2];
#pragma unroll
      for (int mi = 0; mi < 2; ++mi)
        av[mi] = *(const b8*)(sA + (wr * 64 + mi * 32 + fb) * 128 + sw);
#pragma unroll
      for (int ni = 0; ni < 2; ++ni)
        bv[ni] = *(const b8*)(sW + (wc * 64 + ni * 32 + fb) * 128 + sw);
#pragma unroll
      for (int mi = 0; mi < 2; ++mi)
#pragma unroll
        for (int ni = 0; ni < 2; ++ni)
          acc[mi][ni] = __builtin_amdgcn_mfma_f32_32x32x16_bf16(av[mi], bv[ni], acc[mi][ni], 0, 0, 0);
    }
  }

  const float* ebp = eb + (size_t)e * 1024;
#pragma unroll
  for (int mi = 0; mi < 2; ++mi)
#pragma unroll
    for (int r = 0; r < 16; ++r) {
      const int row32 = (r & 3) + 8 * (r >> 2) + 4 * fx;
      const int local = wr * 64 + mi * 32 + row32;
      const int R = slrow[local];
      if (R < 0) continue;
      const float w = slw[local];
#pragma unroll
      for (int ni = 0; ni < 2; ++ni) {
        const int gcol = by * 128 + wc * 64 + ni * 32 + fb;
        const float v = w * (acc[mi][ni][r] + ebp[gcol]);
        if constexpr (PASS == 0) {
          ACC[(size_t)R * 1024 + gcol] = v;
        } else {
          BFBh[(size_t)R * 2048 + gcol] = (__bf16)(ACC[(size_t)R * 1024 + gcol] + v);
        }
      }
    }
}

// --------------------------- prep / elementwise ----------------------------

__global__ void split_w(const float* __restrict__ src, _Float16* __restrict__ dh,
                        _Float16* __restrict__ dl, const size_t n)
{
  const size_t i = ((size_t)blockIdx.x * 256 + threadIdx.x) * 4;
  if (i >= n) return;
  const f4 v = *(const f4*)(src + i);
  h4 hh, ll;
#pragma unroll
  for (int j = 0; j < 4; ++j) {
    const _Float16 h = (_Float16)v[j];
    hh[j] = h;
    ll[j] = (_Float16)((v[j] - (float)h) * 2048.f);
  }
  *(h4*)(dh + i) = hh;
  *(h4*)(dl + i) = ll;
}

__global__ void cvt_bf(const float* __restrict__ src, __bf16* __restrict__ dst, const size_t n)
{
  const size_t i = ((size_t)blockIdx.x * 256 + threadIdx.x) * 4;
  if (i >= n) return;
  const f4 v = *(const f4*)(src + i);
  b4 o;
#pragma unroll
  for (int j = 0; j < 4; ++j) o[j] = (__bf16)v[j];
  *(b4*)(dst + i) = o;
}

// x1 -> cols [0,1024), x2 -> cols [1024,2048) of split planes (lda 2048)
__global__ void prep_x(const float* __restrict__ x1, const float* __restrict__ x2,
                       _Float16* __restrict__ ph, _Float16* __restrict__ pl)
{
  const size_t i = ((size_t)blockIdx.x * 256 + threadIdx.x) * 4;
  const int b = (int)(i >> 11);
  const int c = (int)(i & 2047);
  const float* s = (c < 1024) ? (x1 + (size_t)b * 1024 + c)
                              : (x2 + (size_t)b * 1024 + (c - 1024));
  const f4 v = *(const f4*)s;
  h4 hh, ll;
#pragma unroll
  for (int j = 0; j < 4; ++j) {
    const _Float16 h = (_Float16)v[j];
    hh[j] = h;
    ll[j] = (_Float16)((v[j] - (float)h) * 2048.f);
  }
  *(h4*)(ph + i) = hh;
  *(h4*)(pl + i) = ll;
}

// fold BN-eval into per-col scale/shift: s = g/sqrt(1+eps), t = mb*s + b
__global__ void fold_kernel(const float* g1, const float* b1, const float* mb1,
                            const float* g2, const float* b2, const float* mb2,
                            const float* gf, const float* bf, const float* fb,
                            float* s1, float* t1, float* s2, float* t2,
                            float* fs, float* ft)
{
  const int t = blockIdx.x * 256 + threadIdx.x;
  const float inv = (float)(1.0 / sqrt(1.0 + 1.0e-5));
  if (t < 2048) {
    float a = g1[t] * inv; s1[t] = a; t1[t] = mb1[t] * a + b1[t];
    float c = g2[t] * inv; s2[t] = c; t2[t] = mb2[t] * c + b2[t];
  }
  if (t < 1024) {
    float a = gf[t] * inv; fs[t] = a; ft[t] = fb[t] * a + bf[t];
  }
}

// LayerNorm over 2048 cols -> bf16 out; FUSED gate (top2 softmax -> sel/selw).
// Gate accumulates in f32 (logit error ~1e-6, same scale as trunk error).
__global__ __launch_bounds__(256)
void ln_gate_kernel(const float* __restrict__ xf, __bf16* __restrict__ xb,
                    const float* __restrict__ lg, const float* __restrict__ lb,
                    const float* __restrict__ gw, const float* __restrict__ gb,
                    int* __restrict__ sel, float* __restrict__ selw,
                    const int rowbase, const int CM2)
{
  const int row = blockIdx.x;
  const float* xr = xf + (size_t)row * 2048;
  const int tid = threadIdx.x;
  const int wid = tid >> 6, lane = tid & 63;
  const f4 v0 = *(const f4*)(xr + tid * 4);
  const f4 v1 = *(const f4*)(xr + 1024 + tid * 4);
  double s = 0.0, ss = 0.0;
#pragma unroll
  for (int j = 0; j < 4; ++j) {
    s  += (double)v0[j] + (double)v1[j];
    ss += (double)v0[j] * v0[j] + (double)v1[j] * v1[j];
  }
#pragma unroll
  for (int o = 32; o; o >>= 1) { s += __shfl_xor(s, o); ss += __shfl_xor(ss, o); }
  __shared__ double red[8];
  if (!lane) { red[wid] = s; red[4 + wid] = ss; }
  __syncthreads();
  const double S  = red[0] + red[1] + red[2] + red[3];
  const double SS = red[4] + red[5] + red[6] + red[7];
  const double mu = S * (1.0 / 2048.0);
  const double var = SS * (1.0 / 2048.0) - mu * mu;
  const float inv = (float)(1.0 / sqrt(var + 1.0e-5));
  const float muf = (float)mu;
  f4 o0, o1;
  b4 q0, q1;
#pragma unroll
  for (int j = 0; j < 4; ++j) {
    const int c0 = tid * 4 + j, c1 = 1024 + tid * 4 + j;
    o0[j] = (v0[j] - muf) * inv * lg[c0] + lb[c0];
    o1[j] = (v1[j] - muf) * inv * lg[c1] + lb[c1];
    q0[j] = (__bf16)o0[j];
    q1[j] = (__bf16)o1[j];
  }
  *(b4*)(xb + (size_t)row * 2048 + tid * 4) = q0;
  *(b4*)(xb + (size_t)row * 2048 + 1024 + tid * 4) = q1;

  // ---- fused gate: 16 dots (2 halves x 8 experts), f32 FMA + f32 reduce ----
  float l0[8], l1[8];
#pragma unroll
  for (int e = 0; e < 8; ++e) {
    const f4 w = *(const f4*)(gw + e * 1024 + tid * 4);
    l0[e] = o0[0] * w[0] + o0[1] * w[1] + o0[2] * w[2] + o0[3] * w[3];
    l1[e] = o1[0] * w[0] + o1[1] * w[1] + o1[2] * w[2] + o1[3] * w[3];
  }
#pragma unroll
  for (int o = 32; o; o >>= 1)
#pragma unroll
    for (int e = 0; e < 8; ++e) {
      l0[e] += __shfl_xor(l0[e], o);
      l1[e] += __shfl_xor(l1[e], o);
    }
  __shared__ float red2[4][16];
  if (!lane)
#pragma unroll
    for (int e = 0; e < 8; ++e) { red2[wid][e] = l0[e]; red2[wid][8 + e] = l1[e]; }
  __syncthreads();
  if (tid < 2) {                     // tid 0: half 0, tid 1: half 1
    const int h = tid;
    float lg8[8];
#pragma unroll
    for (int e = 0; e < 8; ++e)
      lg8[e] = red2[0][h * 8 + e] + red2[1][h * 8 + e] + red2[2][h * 8 + e]
             + red2[3][h * 8 + e] + gb[e];
    int i0 = 0;
    for (int e = 1; e < 8; ++e) if (lg8[e] > lg8[i0]) i0 = e;
    int i1 = -1;
    for (int e = 0; e < 8; ++e) if (e != i0 && (i1 < 0 || lg8[e] > lg8[i1])) i1 = e;
    const double p = exp((double)lg8[i1] - (double)lg8[i0]);
    const double z = 1.0 + p;
    int* sp = sel + h * CM2 + (size_t)(rowbase + row) * 2;
    float* wp = selw + h * CM2 + (size_t)(rowbase + row) * 2;
    sp[0] = i0; wp[0] = (float)(1.0 / z);
    sp[1] = i1; wp[1] = (float)(p / z);
  }
}

// wave-aggregated per-(half,rank) expert histogram: <=16 atomics per wave
__global__ void count_kernel(const int* __restrict__ sel, int* __restrict__ cnt,
                             const int CM)
{
  const int idx = blockIdx.x * 256 + threadIdx.x;   // h*CM + row
  const bool valid = idx < 2 * CM;
  const int h = (idx / CM) & 1;                     // wave-uniform (CM % 64 == 0)
  const int lane = threadIdx.x & 63;
#pragma unroll
  for (int r = 0; r < 2; ++r) {
    const int e = valid ? sel[idx * 2 + r] : -1;
    const int g = h * 2 + r;
    for (int ee = 0; ee < 8; ++ee) {
      const unsigned long long mask = __ballot(e == ee);
      if (mask && lane == __ffsll((unsigned long long)mask) - 1)
        atomicAdd(&cnt[g * 8 + ee], __popcll(mask));
    }
  }
}

// 128-aligned segment starts + block->expert maps for 4 groups (h,r)
__global__ void prefix_kernel(const int* __restrict__ cnt, int* __restrict__ cursor,
                              int* __restrict__ blkexp, const int NBLK)
{
  const int tid = threadIdx.x;
  for (int i = tid; i < 4 * NBLK; i += 256) blkexp[i] = -1;
  __syncthreads();
  if (tid < 32) {
    const int g = tid >> 3, e = tid & 7;      // g = h*2 + r
    int off = 0;
    for (int j = 0; j < e; ++j) off += ((cnt[g * 8 + j] + 127) >> 7) << 7;
    cursor[g * 8 + e] = off;
    const int nb = (cnt[g * 8 + e] + 127) >> 7;
    for (int b = 0; b < nb; ++b) blkexp[g * NBLK + (off >> 7) + b] = e;
  }
}

// fill per-(half,rank) work-lists via ballot aggregation: one atomic per
// (wave, expert) with popcount; lanes derive slots from mask prefix-pop.
__global__ void scatter_kernel(const int* __restrict__ sel, const float* __restrict__ selw,
                               int* __restrict__ cursor,
                               int* __restrict__ lrow, float* __restrict__ lw,
                               const int CM, const int LCAP)
{
  const int idx = blockIdx.x * 256 + threadIdx.x;   // h*CM + row
  const bool valid = idx < 2 * CM;
  const int h = (idx / CM) & 1;                     // wave-uniform (CM % 64 == 0)
  const int R = valid ? (idx - (idx / CM) * CM) : 0;
  const int lane = threadIdx.x & 63;
#pragma unroll
  for (int r = 0; r < 2; ++r) {
    const int e = valid ? sel[idx * 2 + r] : -1;
    const int g = h * 2 + r;
    int pos = -1;
    for (int ee = 0; ee < 8; ++ee) {
      const unsigned long long mask = __ballot(e == ee);
      if (mask) {
        const int leader = __ffsll((unsigned long long)mask) - 1;
        int base = 0;
        if (lane == leader) base = atomicAdd(&cursor[g * 8 + ee], __popcll(mask));
        base = __shfl(base, leader);
        if (e == ee)
          pos = base + __popcll(mask & ((1ull << lane) - 1ull));
      }
    }
    if (valid) {
      lrow[g * LCAP + pos] = R;
      lw[g * LCAP + pos] = selw[idx * 2 + r];
    }
  }
}

// out[row] = dot(fused_row, reg_w) + reg_b
__global__ __launch_bounds__(256)
void reg_kernel(const float* __restrict__ xf, const float* __restrict__ rw,
                const float* __restrict__ rb, float* __restrict__ out)
{
  const int wid = threadIdx.x >> 6, lane = threadIdx.x & 63;
  const int row = blockIdx.x * 4 + wid;
  const float* xr = xf + (size_t)row * 1024;
  double acc = 0.0;
#pragma unroll
  for (int i = 0; i < 4; ++i) {
    const int f = (lane + 64 * i) * 4;
    const f4 a = *(const f4*)(xr + f);
    const f4 w = *(const f4*)(rw + f);
    acc += (double)a[0] * w[0] + (double)a[1] * w[1] + (double)a[2] * w[2] + (double)a[3] * w[3];
  }
#pragma unroll
  for (int o = 32; o; o >>= 1) acc += __shfl_xor(acc, o);
  if (!lane) out[row] = (float)(acc + (double)rb[0]);
}

// ---------------------------------------------------------------------------

extern "C" void kernel_launch(void* const* d_in, const int* in_sizes, int n_in,
                              void* d_out, int out_size, void* d_ws, size_t ws_size,
                              hipStream_t stream)
{
  (void)in_sizes; (void)n_in; (void)out_size;
  const float* x1    = (const float*)d_in[0];
  const float* x2    = (const float*)d_in[1];
  const float* p1_w  = (const float*)d_in[2];
  const float* p1_b  = (const float*)d_in[3];
  const float* p2_w  = (const float*)d_in[4];
  const float* p2_b  = (const float*)d_in[5];
  const float* m1_w  = (const float*)d_in[6];
  const float* m1_b  = (const float*)d_in[7];
  const float* bn1_g = (const float*)d_in[8];
  const float* bn1_b = (const float*)d_in[9];
  const float* m2_w  = (const float*)d_in[10];
  const float* m2_b  = (const float*)d_in[11];
  const float* bn2_g = (const float*)d_in[12];
  const float* bn2_b = (const float*)d_in[13];
  const float* m3_w  = (const float*)d_in[14];
  const float* m3_b  = (const float*)d_in[15];
  const float* ln_g  = (const float*)d_in[16];
  const float* ln_b  = (const float*)d_in[17];
  const float* ex_w  = (const float*)d_in[18];
  const float* ex_b  = (const float*)d_in[19];
  const float* gate_w= (const float*)d_in[20];
  const float* gate_b= (const float*)d_in[21];
  const float* fus_w = (const float*)d_in[22];
  const float* fus_b = (const float*)d_in[23];
  const float* bnf_g = (const float*)d_in[24];
  const float* bnf_b = (const float*)d_in[25];
  const float* reg_w = (const float*)d_in[26];
  const float* reg_b = (const float*)d_in[27];

  char* ws = (char*)d_ws;
  size_t off = 0;
  auto alloc = [&](size_t bytes) { size_t o = off; off += (bytes + 255) & ~(size_t)255; return o; };

  // ---- fixed region: trunk split weights + folded vectors (~56 MB) ----
  const size_t oWHp1 = alloc((size_t)1048576 * 2), oWLp1 = alloc((size_t)1048576 * 2);
  const size_t oWHp2 = alloc((size_t)1048576 * 2), oWLp2 = alloc((size_t)1048576 * 2);
  const size_t oWHm1 = alloc((size_t)4194304 * 2), oWLm1 = alloc((size_t)4194304 * 2);
  const size_t oWHm2 = alloc((size_t)4194304 * 2), oWLm2 = alloc((size_t)4194304 * 2);
  const size_t oWHm3 = alloc((size_t)4194304 * 2), oWLm3 = alloc((size_t)4194304 * 2);
  const size_t oS1 = alloc(2048 * 4), oT1 = alloc(2048 * 4);
  const size_t oS2 = alloc(2048 * 4), oT2 = alloc(2048 * 4);
  const size_t oFS = alloc(1024 * 4), oFT = alloc(1024 * 4);
  const size_t oCnt = alloc(32 * 4), oCur = alloc(32 * 4);
  const size_t fixedEnd = off;

  // ---- choose outer chunk CM (MoE batch) so everything fits ws_size ----
  int CM = BROWS;
  while (CM > 2048) {
    const int ct = (CM < 4096) ? CM : 4096;
    const size_t nblk = (size_t)CM / 128 + 8;
    const size_t lcap = nblk * 128;
    const size_t need = fixedEnd
                      + 4 * ((size_t)ct * 4096 + 256)   // P planes
                      + 2 * ((size_t)CM * 4096 + 256)   // BFA + BFB
                      + 2 * ((size_t)CM * 16 + 256)     // sel + selw
                      + 2 * (4 * lcap * 4 + 256)        // lrow + lw (4 groups)
                      + (4 * nblk * 4 + 256) + 8192;    // blkexp
    if (ws_size >= need) break;
    CM >>= 1;
  }
  const int CT = (CM < 4096) ? CM : 4096;
  const int NBLK = CM / 128 + 8;
  const int LCAP = NBLK * 128;

  const size_t oP    = alloc(4 * (size_t)CT * 4096);   // trunk planes / ACC / F32fus
  const size_t oBFA  = alloc((size_t)CM * 4096);
  const size_t oBFB  = alloc((size_t)CM * 4096);
  const size_t oSel  = alloc((size_t)CM * 16);
  const size_t oSelw = alloc((size_t)CM * 16);
  const size_t oLrow = alloc((size_t)4 * LCAP * 4);
  const size_t oLw   = alloc((size_t)4 * LCAP * 4);
  const size_t oBlk  = alloc((size_t)4 * NBLK * 4);

  _Float16* WHp1 = (_Float16*)(ws + oWHp1); _Float16* WLp1 = (_Float16*)(ws + oWLp1);
  _Float16* WHp2 = (_Float16*)(ws + oWHp2); _Float16* WLp2 = (_Float16*)(ws + oWLp2);
  _Float16* WHm1 = (_Float16*)(ws + oWHm1); _Float16* WLm1 = (_Float16*)(ws + oWLm1);
  _Float16* WHm2 = (_Float16*)(ws + oWHm2); _Float16* WLm2 = (_Float16*)(ws + oWLm2);
  _Float16* WHm3 = (_Float16*)(ws + oWHm3); _Float16* WLm3 = (_Float16*)(ws + oWLm3);
  // MoE weights alias the m-layer split weights (converted AFTER the trunk,
  // re-split at the top of each outer iteration):
  __bf16* WBex = (__bf16*)(ws + oWHm1);   // 16 MB over WHm1+WLm1
  __bf16* WBfu = (__bf16*)(ws + oWHm2);   //  4 MB over WHm2
  _Float16* PH0 = (_Float16*)(ws + oP);
  _Float16* PL0 = (_Float16*)(ws + oP + (size_t)CT * 4096);
  _Float16* PH1 = (_Float16*)(ws + oP + 2 * (size_t)CT * 4096);
  _Float16* PL1 = (_Float16*)(ws + oP + 3 * (size_t)CT * 4096);
  float* F32    = (float*)(ws + oP);      // CT x 2048 f32 (planes 0-1)
  float* ACC    = (float*)(ws + oP);      // CM x 1024 f32 (whole P)
  float* F32fus = (float*)(ws + oP);      // CM x 1024 f32 (whole P)
  __bf16* BFA = (__bf16*)(ws + oBFA);     // LN output bf16, CM x 2048
  __bf16* BFB = (__bf16*)(ws + oBFB);     // moe concat bf16, CM x 2048
  int*   sel  = (int*)(ws + oSel);
  float* selw = (float*)(ws + oSelw);
  int*   lrow = (int*)(ws + oLrow);
  float* lw   = (float*)(ws + oLw);
  int*   blkexp = (int*)(ws + oBlk);
  int*   cnt = (int*)(ws + oCnt);
  int*   cur = (int*)(ws + oCur);
  float* s1v = (float*)(ws + oS1); float* t1v = (float*)(ws + oT1);
  float* s2v = (float*)(ws + oS2); float* t2v = (float*)(ws + oT2);
  float* fsv = (float*)(ws + oFS); float* ftv = (float*)(ws + oFT);

  const dim3 T(256);
  // ---- once: fold BN vectors, p-layer splits (never clobbered) ----
  fold_kernel<<<8, T, 0, stream>>>(bn1_g, bn1_b, m1_b, bn2_g, bn2_b, m2_b,
                                   bnf_g, bnf_b, fus_b, s1v, t1v, s2v, t2v, fsv, ftv);
  split_w<<<1024, T, 0, stream>>>(p1_w, WHp1, WLp1, 1048576);
  split_w<<<1024, T, 0, stream>>>(p2_w, WHp2, WLp2, 1048576);

  const dim3 GP(CT / 128, 8, 2), GT16(CT / 128, 16, 1), GM(NBLK, 8), GF(CM / 128, 8);
  for (int m0 = 0; m0 < BROWS; m0 += CM) {
    // m-layer split weights (region shared with WBex/WBfu -> re-split)
    split_w<<<4096, T, 0, stream>>>(m1_w, WHm1, WLm1, 4194304);
    split_w<<<4096, T, 0, stream>>>(m2_w, WHm2, WLm2, 4194304);
    split_w<<<4096, T, 0, stream>>>(m3_w, WHm3, WLm3, 4194304);

    // ---- trunk, inner-chunked at CT ----
    for (int r0 = 0; r0 < CM; r0 += CT) {
      const float* x1c = x1 + (size_t)(m0 + r0) * 1024;
      const float* x2c = x2 + (size_t)(m0 + r0) * 1024;
      prep_x<<<CT * 2, T, 0, stream>>>(x1c, x2c, PH0, PL0);
      // p1 + p2 merged (z selects weight set; A/C offset by 1024 cols)
      gemm_split<0><<<GP, T, 0, stream>>>(PH0, PL0, WHp1, WLp1, WHp2, WLp2,
                                          2048, 1024, 1024,
                                          PH1, PL1, nullptr, 2048,
                                          p1_b, nullptr, p2_b, 1024);
      gemm_split<1><<<GT16, T, 0, stream>>>(PH1, PL1, WHm1, WLm1, WHm1, WLm1,
                                            2048, 2048, 2048,
                                            PH0, PL0, nullptr, 2048,
                                            s1v, t1v, s1v, 0);
      gemm_split<1><<<GT16, T, 0, stream>>>(PH0, PL0, WHm2, WLm2, WHm2, WLm2,
                                            2048, 2048, 2048,
                                            PH1, PL1, nullptr, 2048,
                                            s2v, t2v, s2v, 0);
      gemm_split<2><<<GT16, T, 0, stream>>>(PH1, PL1, WHm3, WLm3, WHm3, WLm3,
                                            2048, 2048, 2048,
                                            nullptr, nullptr, F32, 2048,
                                            m3_b, nullptr, m3_b, 0);
      // LN + fused gate (writes BFA bf16 + sel/selw; no F32 writeback)
      ln_gate_kernel<<<CT, T, 0, stream>>>(F32, BFA + (size_t)r0 * 2048,
                                           ln_g, ln_b, gate_w, gate_b,
                                           sel, selw, r0, CM * 2);
    }

    // ---- MoE weights (clobber m-layer splits now that trunk is done) ----
    cvt_bf<<<8192, T, 0, stream>>>(ex_w, WBex, 8388608);
    cvt_bf<<<2048, T, 0, stream>>>(fus_w, WBfu, 2097152);

    // ---- full-batch MoE (ballot-aggregated bucketing) ----
    hipMemsetAsync(cnt, 0, 32 * 4, stream);
    count_kernel<<<(2 * CM + 255) / 256, T, 0, stream>>>(sel, cnt, CM);
    prefix_kernel<<<1, T, 0, stream>>>(cnt, cur, blkexp, NBLK);
    hipMemsetAsync(lrow, 0xFF, (size_t)4 * LCAP * 4, stream);
    scatter_kernel<<<(2 * CM + 255) / 256, T, 0, stream>>>(sel, selw, cur, lrow, lw, CM, LCAP);
    for (int h = 0; h < 2; ++h) {
      const int g0 = h * 2, g1 = h * 2 + 1;
      gemm_moe<0><<<GM, T, 0, stream>>>(BFA + h * 1024, WBex,
                                        lrow + (size_t)g0 * LCAP, lw + (size_t)g0 * LCAP,
                                        blkexp + g0 * NBLK, ex_b, ACC, nullptr);
      gemm_moe<1><<<GM, T, 0, stream>>>(BFA + h * 1024, WBex,
                                        lrow + (size_t)g1 * LCAP, lw + (size_t)g1 * LCAP,
                                        blkexp + g1 * NBLK, ex_b, ACC, BFB + h * 1024);
    }

    // ---- fus + reg on the full outer chunk ----
    gemm_fus<<<GF, T, 0, stream>>>(BFB, WBfu, 2048, 2048, 2048, F32fus, 1024, fsv, ftv);
    reg_kernel<<<CM / 4, T, 0, stream>>>(F32fus, reg_w, reg_b, (float*)d_out + m0);
  }
}

// Round 9
// 1817.073 us; speedup vs baseline: 1.1337x; 1.1337x over previous
//
#include <hip/hip_runtime.h>
#include <stdint.h>
#include <math.h>

#define BROWS 16384

typedef _Float16 h8 __attribute__((ext_vector_type(8)));
typedef _Float16 h4 __attribute__((ext_vector_type(4)));
typedef __bf16   b8 __attribute__((ext_vector_type(8)));
typedef __bf16   b4 __attribute__((ext_vector_type(4)));
typedef float    f4 __attribute__((ext_vector_type(4)));

typedef __attribute__((address_space(3))) char       lds_char;
typedef __attribute__((address_space(1))) const char gbl_char;

// async global->LDS, 16B per lane; LDS dest = wave-uniform base + lane*16
// (global SOURCE address is per-lane -> usable as gather AND as pre-swizzle)
__device__ __forceinline__ void gload16(const void* g, void* l) {
  __builtin_amdgcn_global_load_lds((const gbl_char*)(uintptr_t)g,
                                   (lds_char*)(uintptr_t)l, 16, 0, 0);
}

// BK=64 tile: [128 rows][64 halfs] = 16KB/plane, row stride 128B.
// LDS(row, cb) holds global colblock cb^(row&7)  [staged via pre-swizzled
// per-lane global source colbyte ((l&7)^(l>>3))*16, linear LDS dest].
// 16x16x32 fragment read at colblock ((ks*4 + (lane>>4)) ^ (lane&7)):
// measured conflict-free (round 7: SQ_LDS_BANK_CONFLICT == 0).

// ---------------------------------------------------------------------------
// fp16 2-term split GEMM:  C = A @ W^T (+epilogue), A = Ah + Al/2048,
// W = Wh + Wl/2048, row-major, K contiguous. blockIdx.z selects second
// weight set / bias and offsets A,C by zoff (merged p1+p2 launch).
// EPI 0: y += v0[col]; write split planes Ch/Cl          (p1, p2)
// EPI 1: y = relu(y*v0[col] + v1[col]); write Ch/Cl      (m1, m2)
// EPI 2: Cf = y + v0[col]  (f32)                          (m3)
// ---------------------------------------------------------------------------
template<int EPI>
__global__ __launch_bounds__(256, 2)
void gemm_split(const _Float16* __restrict__ Ah, const _Float16* __restrict__ Al,
                const _Float16* __restrict__ Wh, const _Float16* __restrict__ Wl,
                const _Float16* __restrict__ WhB, const _Float16* __restrict__ WlB,
                const int lda, const int ldw, const int K,
                _Float16* __restrict__ Ch, _Float16* __restrict__ Cl,
                float* __restrict__ Cf, const int ldc,
                const float* __restrict__ v0, const float* __restrict__ v1,
                const float* __restrict__ v0B, const int zoff)
{
  __shared__ char smem[65536];
  char* const sAh = smem;
  char* const sAl = smem + 16384;
  char* const sWh = smem + 32768;
  char* const sWl = smem + 49152;

  if (blockIdx.z) {               // wave-uniform select (p2 of the merged pair)
    Wh = WhB; Wl = WlB; v0 = v0B;
    Ah += zoff; Al += zoff; Ch += zoff; Cl += zoff;
  }

  const int tid  = threadIdx.x;
  const int wid  = tid >> 6, lane = tid & 63;
  const int bm = blockIdx.x, bn = blockIdx.y;
  const int wr = wid >> 1, wc = wid & 1;          // 2x2 waves, 64x64 each
  const int sr  = lane >> 3;                      // staging row-in-8
  const int scb = ((lane & 7) ^ sr) * 16;         // pre-swizzled source colbyte
  const int fr  = lane & 15;                      // fragment row
  const int sw0 = ((lane >> 4) ^ (lane & 7)) * 16;        // read swz, ks=0
  const int sw1 = ((4 + (lane >> 4)) ^ (lane & 7)) * 16;  // read swz, ks=1

  f4 accA[4][4] = {};
  f4 accB[4][4] = {};

  const size_t arow0 = (size_t)bm * 128;
  const size_t wrow0 = (size_t)bn * 128;

  for (int k0 = 0; k0 < K; k0 += 64) {
    __syncthreads();
#pragma unroll
    for (int i = 0; i < 4; ++i) {
      const int rb = wid * 32 + i * 8;
      const size_t ga = (arow0 + rb + sr) * (size_t)lda + k0;
      const size_t gw = (wrow0 + rb + sr) * (size_t)ldw + k0;
      const int lo = rb * 128;                    // wave-uniform LDS base
      gload16((const char*)(Ah + ga) + scb, sAh + lo);
      gload16((const char*)(Al + ga) + scb, sAl + lo);
      gload16((const char*)(Wh + gw) + scb, sWh + lo);
      gload16((const char*)(Wl + gw) + scb, sWl + lo);
    }
    __syncthreads();

#pragma unroll
    for (int ks = 0; ks < 2; ++ks) {
      const int sw = ks ? sw1 : sw0;
      h8 ah[4], al[4], bh[4], bl[4];
#pragma unroll
      for (int mi = 0; mi < 4; ++mi) {
        const int r = (wr * 64 + mi * 16 + fr) * 128 + sw;
        ah[mi] = *(const h8*)(sAh + r);
        al[mi] = *(const h8*)(sAl + r);
      }
#pragma unroll
      for (int ni = 0; ni < 4; ++ni) {
        const int r = (wc * 64 + ni * 16 + fr) * 128 + sw;
        bh[ni] = *(const h8*)(sWh + r);
        bl[ni] = *(const h8*)(sWl + r);
      }
#pragma unroll
      for (int mi = 0; mi < 4; ++mi)
#pragma unroll
        for (int ni = 0; ni < 4; ++ni) {
          accA[mi][ni] = __builtin_amdgcn_mfma_f32_16x16x32_f16(ah[mi], bh[ni], accA[mi][ni], 0, 0, 0);
          accB[mi][ni] = __builtin_amdgcn_mfma_f32_16x16x32_f16(ah[mi], bl[ni], accB[mi][ni], 0, 0, 0);
          accB[mi][ni] = __builtin_amdgcn_mfma_f32_16x16x32_f16(al[mi], bh[ni], accB[mi][ni], 0, 0, 0);
        }
    }
  }

  const int rg = (lane >> 4) * 4;                 // C/D: col=lane&15, row=(lane>>4)*4+j
#pragma unroll
  for (int mi = 0; mi < 4; ++mi)
#pragma unroll
    for (int ni = 0; ni < 4; ++ni) {
      const int gcol = bn * 128 + wc * 64 + ni * 16 + fr;
      const float a0 = v0[gcol];
      const float a1 = (EPI == 1) ? v1[gcol] : 0.f;
#pragma unroll
      for (int j = 0; j < 4; ++j) {
        const size_t grow = arow0 + wr * 64 + mi * 16 + rg + j;
        float y = accA[mi][ni][j] + accB[mi][ni][j] * (1.f / 2048.f);
        const size_t off = grow * (size_t)ldc + gcol;
        if constexpr (EPI == 0) {
          y += a0;
          const _Float16 hh = (_Float16)y;
          Ch[off] = hh;
          Cl[off] = (_Float16)((y - (float)hh) * 2048.f);
        } else if constexpr (EPI == 1) {
          y = fmaxf(fmaf(y, a0, a1), 0.f);
          const _Float16 hh = (_Float16)y;
          Ch[off] = hh;
          Cl[off] = (_Float16)((y - (float)hh) * 2048.f);
        } else {
          Cf[off] = y + a0;
        }
      }
    }
}

// ---------------------------------------------------------------------------
// bf16 GEMM for the fus layer: Cf = (A @ W^T)*v0[col] + v1[col]   (BK=64)
// ---------------------------------------------------------------------------
__global__ __launch_bounds__(256, 2)
void gemm_fus(const __bf16* __restrict__ A, const __bf16* __restrict__ W,
              const int lda, const int ldw, const int K,
              float* __restrict__ Cf, const int ldc,
              const float* __restrict__ v0, const float* __restrict__ v1)
{
  __shared__ char smem[32768];
  char* const sA = smem;
  char* const sW = smem + 16384;

  const int tid  = threadIdx.x;
  const int wid  = tid >> 6, lane = tid & 63;
  const int bm = blockIdx.x, bn = blockIdx.y;
  const int wr = wid >> 1, wc = wid & 1;
  const int sr  = lane >> 3;
  const int scb = ((lane & 7) ^ sr) * 16;
  const int fr  = lane & 15;
  const int sw0 = ((lane >> 4) ^ (lane & 7)) * 16;
  const int sw1 = ((4 + (lane >> 4)) ^ (lane & 7)) * 16;

  f4 acc[4][4] = {};

  const size_t arow0 = (size_t)bm * 128;
  const size_t wrow0 = (size_t)bn * 128;

  for (int k0 = 0; k0 < K; k0 += 64) {
    __syncthreads();
#pragma unroll
    for (int i = 0; i < 4; ++i) {
      const int rb = wid * 32 + i * 8;
      const size_t ga = (arow0 + rb + sr) * (size_t)lda + k0;
      const size_t gw = (wrow0 + rb + sr) * (size_t)ldw + k0;
      const int lo = rb * 128;
      gload16((const char*)(A + ga) + scb, sA + lo);
      gload16((const char*)(W + gw) + scb, sW + lo);
    }
    __syncthreads();

#pragma unroll
    for (int ks = 0; ks < 2; ++ks) {
      const int sw = ks ? sw1 : sw0;
      b8 av[4], bv[4];
#pragma unroll
      for (int mi = 0; mi < 4; ++mi)
        av[mi] = *(const b8*)(sA + (wr * 64 + mi * 16 + fr) * 128 + sw);
#pragma unroll
      for (int ni = 0; ni < 4; ++ni)
        bv[ni] = *(const b8*)(sW + (wc * 64 + ni * 16 + fr) * 128 + sw);
#pragma unroll
      for (int mi = 0; mi < 4; ++mi)
#pragma unroll
        for (int ni = 0; ni < 4; ++ni)
          acc[mi][ni] = __builtin_amdgcn_mfma_f32_16x16x32_bf16(av[mi], bv[ni], acc[mi][ni], 0, 0, 0);
    }
  }

  const int rg = (lane >> 4) * 4;
#pragma unroll
  for (int mi = 0; mi < 4; ++mi)
#pragma unroll
    for (int j = 0; j < 4; ++j) {
      const size_t grow = arow0 + wr * 64 + mi * 16 + rg + j;
#pragma unroll
      for (int ni = 0; ni < 4; ++ni) {
        const int gcol = bn * 128 + wc * 64 + ni * 16 + fr;
        Cf[grow * (size_t)ldc + gcol] = fmaf(acc[mi][ni][j], v0[gcol], v1[gcol]);
      }
    }
}

// ---------------------------------------------------------------------------
// gathered per-(half,rank) expert GEMM (BK=64). Block bx: 128 worklist rows,
// all expert blkexp[bx]; by = 128-col tile. A rows gathered via per-lane
// global_load_lds source addresses (pre-swizzled cols).
// PASS 0 (rank 0): ACCb[row][col] = bf16( w * ((A[row]@We^T)[col] + be[col]) )
// PASS 1 (rank 1): BFBh[row][col] = bf16( ACCb[row][col] + w * (...) )
// Row-unique writers per pass -> bit-deterministic regardless of scatter order.
// ---------------------------------------------------------------------------
template<int PASS>
__global__ __launch_bounds__(256, 2)
void gemm_moe(const __bf16* __restrict__ A,      // BFA + h*1024, lda 2048
              const __bf16* __restrict__ Wall,   // 8 x (1024x1024) bf16
              const int* __restrict__ lrow, const float* __restrict__ lw,
              const int* __restrict__ blkexp,
              const float* __restrict__ eb,      // ex_b (8x1024)
              __bf16* __restrict__ ACCb,         // CM x 1024 bf16
              __bf16* __restrict__ BFBh)         // BFB + h*1024, ld 2048
{
  const int bx = blockIdx.x, by = blockIdx.y;
  const int e = blkexp[bx];
  if (e < 0) return;                              // fully-pad block

  __shared__ char smem[32768];
  __shared__ int   slrow[128];
  __shared__ float slw[128];
  char* const sA = smem;
  char* const sW = smem + 16384;

  const int tid  = threadIdx.x;
  const int wid  = tid >> 6, lane = tid & 63;
  if (tid < 128) { slrow[tid] = lrow[bx * 128 + tid]; slw[tid] = lw[bx * 128 + tid]; }
  __syncthreads();

  const __bf16* W = Wall + (size_t)e * 1048576 + (size_t)by * 131072;

  const int wr = wid >> 1, wc = wid & 1;
  const int sr  = lane >> 3;
  const int scb = ((lane & 7) ^ sr) * 16;
  const int fr  = lane & 15;
  const int sw0 = ((lane >> 4) ^ (lane & 7)) * 16;
  const int sw1 = ((4 + (lane >> 4)) ^ (lane & 7)) * 16;

  // per-lane gathered A base pointers (4 staging loads per wave)
  const char* abase[4];
#pragma unroll
  for (int i = 0; i < 4; ++i) {
    int s = slrow[wid * 32 + i * 8 + sr];
    if (s < 0) s = 0;
    abase[i] = (const char*)(A + (size_t)s * 2048) + scb;
  }

  f4 acc[4][4] = {};

  for (int k0 = 0; k0 < 1024; k0 += 64) {
    __syncthreads();
#pragma unroll
    for (int i = 0; i < 4; ++i) {
      const int rb = wid * 32 + i * 8;
      const int lo = rb * 128;
      gload16(abase[i] + (size_t)k0 * 2, sA + lo);
      gload16((const char*)(W + (size_t)(rb + sr) * 1024 + k0) + scb, sW + lo);
    }
    __syncthreads();

#pragma unroll
    for (int ks = 0; ks < 2; ++ks) {
      const int sw = ks ? sw1 : sw0;
      b8 av[4], bv[4];
#pragma unroll
      for (int mi = 0; mi < 4; ++mi)
        av[mi] = *(const b8*)(sA + (wr * 64 + mi * 16 + fr) * 128 + sw);
#pragma unroll
      for (int ni = 0; ni < 4; ++ni)
        bv[ni] = *(const b8*)(sW + (wc * 64 + ni * 16 + fr) * 128 + sw);
#pragma unroll
      for (int mi = 0; mi < 4; ++mi)
#pragma unroll
        for (int ni = 0; ni < 4; ++ni)
          acc[mi][ni] = __builtin_amdgcn_mfma_f32_16x16x32_bf16(av[mi], bv[ni], acc[mi][ni], 0, 0, 0);
    }
  }

  const int rg = (lane >> 4) * 4;
  const float* ebp = eb + (size_t)e * 1024;
#pragma unroll
  for (int mi = 0; mi < 4; ++mi)
#pragma unroll
    for (int j = 0; j < 4; ++j) {
      const int local = wr * 64 + mi * 16 + rg + j;
      const int R = slrow[local];
      if (R < 0) continue;
      const float w = slw[local];
#pragma unroll
      for (int ni = 0; ni < 4; ++ni) {
        const int gcol = by * 128 + wc * 64 + ni * 16 + fr;
        const float v = w * (acc[mi][ni][j] + ebp[gcol]);
        if constexpr (PASS == 0) {
          ACCb[(size_t)R * 1024 + gcol] = (__bf16)v;
        } else {
          BFBh[(size_t)R * 2048 + gcol] = (__bf16)((float)ACCb[(size_t)R * 1024 + gcol] + v);
        }
      }
    }
}

// --------------------------- prep / elementwise ----------------------------

__global__ void split_w(const float* __restrict__ src, _Float16* __restrict__ dh,
                        _Float16* __restrict__ dl, const size_t n)
{
  const size_t i = ((size_t)blockIdx.x * 256 + threadIdx.x) * 4;
  if (i >= n) return;
  const f4 v = *(const f4*)(src + i);
  h4 hh, ll;
#pragma unroll
  for (int j = 0; j < 4; ++j) {
    const _Float16 h = (_Float16)v[j];
    hh[j] = h;
    ll[j] = (_Float16)((v[j] - (float)h) * 2048.f);
  }
  *(h4*)(dh + i) = hh;
  *(h4*)(dl + i) = ll;
}

__global__ void cvt_bf(const float* __restrict__ src, __bf16* __restrict__ dst, const size_t n)
{
  const size_t i = ((size_t)blockIdx.x * 256 + threadIdx.x) * 4;
  if (i >= n) return;
  const f4 v = *(const f4*)(src + i);
  b4 o;
#pragma unroll
  for (int j = 0; j < 4; ++j) o[j] = (__bf16)v[j];
  *(b4*)(dst + i) = o;
}

// x1 -> cols [0,1024), x2 -> cols [1024,2048) of split planes (lda 2048)
__global__ void prep_x(const float* __restrict__ x1, const float* __restrict__ x2,
                       _Float16* __restrict__ ph, _Float16* __restrict__ pl)
{
  const size_t i = ((size_t)blockIdx.x * 256 + threadIdx.x) * 4;
  const int b = (int)(i >> 11);
  const int c = (int)(i & 2047);
  const float* s = (c < 1024) ? (x1 + (size_t)b * 1024 + c)
                              : (x2 + (size_t)b * 1024 + (c - 1024));
  const f4 v = *(const f4*)s;
  h4 hh, ll;
#pragma unroll
  for (int j = 0; j < 4; ++j) {
    const _Float16 h = (_Float16)v[j];
    hh[j] = h;
    ll[j] = (_Float16)((v[j] - (float)h) * 2048.f);
  }
  *(h4*)(ph + i) = hh;
  *(h4*)(pl + i) = ll;
}

// fold BN-eval into per-col scale/shift: s = g/sqrt(1+eps), t = mb*s + b
__global__ void fold_kernel(const float* g1, const float* b1, const float* mb1,
                            const float* g2, const float* b2, const float* mb2,
                            const float* gf, const float* bf, const float* fb,
                            float* s1, float* t1, float* s2, float* t2,
                            float* fs, float* ft)
{
  const int t = blockIdx.x * 256 + threadIdx.x;
  const float inv = (float)(1.0 / sqrt(1.0 + 1.0e-5));
  if (t < 2048) {
    float a = g1[t] * inv; s1[t] = a; t1[t] = mb1[t] * a + b1[t];
    float c = g2[t] * inv; s2[t] = c; t2[t] = mb2[t] * c + b2[t];
  }
  if (t < 1024) {
    float a = gf[t] * inv; fs[t] = a; ft[t] = fb[t] * a + bf[t];
  }
}

// LayerNorm over 2048 cols -> bf16 out; FUSED gate (top2 softmax -> sel/selw).
// LN stats in f64 (guards logit precision); gate dots in f32 (error ~3e-6
// vs min top-2 gap ~1e-5 -- validated round 8, identical absmax).
__global__ __launch_bounds__(256)
void ln_gate_kernel(const float* __restrict__ xf, __bf16* __restrict__ xb,
                    const float* __restrict__ lg, const float* __restrict__ lb,
                    const float* __restrict__ gw, const float* __restrict__ gb,
                    int* __restrict__ sel, float* __restrict__ selw,
                    const int rowbase, const int CM2)
{
  const int row = blockIdx.x;
  const float* xr = xf + (size_t)row * 2048;
  const int tid = threadIdx.x;
  const int wid = tid >> 6, lane = tid & 63;
  const f4 v0 = *(const f4*)(xr + tid * 4);
  const f4 v1 = *(const f4*)(xr + 1024 + tid * 4);
  double s = 0.0, ss = 0.0;
#pragma unroll
  for (int j = 0; j < 4; ++j) {
    s  += (double)v0[j] + (double)v1[j];
    ss += (double)v0[j] * v0[j] + (double)v1[j] * v1[j];
  }
#pragma unroll
  for (int o = 32; o; o >>= 1) { s += __shfl_xor(s, o); ss += __shfl_xor(ss, o); }
  __shared__ double red[8];
  if (!lane) { red[wid] = s; red[4 + wid] = ss; }
  __syncthreads();
  const double S  = red[0] + red[1] + red[2] + red[3];
  const double SS = red[4] + red[5] + red[6] + red[7];
  const double mu = S * (1.0 / 2048.0);
  const double var = SS * (1.0 / 2048.0) - mu * mu;
  const float inv = (float)(1.0 / sqrt(var + 1.0e-5));
  const float muf = (float)mu;
  f4 o0, o1;
  b4 q0, q1;
#pragma unroll
  for (int j = 0; j < 4; ++j) {
    const int c0 = tid * 4 + j, c1 = 1024 + tid * 4 + j;
    o0[j] = (v0[j] - muf) * inv * lg[c0] + lb[c0];
    o1[j] = (v1[j] - muf) * inv * lg[c1] + lb[c1];
    q0[j] = (__bf16)o0[j];
    q1[j] = (__bf16)o1[j];
  }
  *(b4*)(xb + (size_t)row * 2048 + tid * 4) = q0;
  *(b4*)(xb + (size_t)row * 2048 + 1024 + tid * 4) = q1;

  // ---- fused gate: 16 dots (2 halves x 8 experts), f32 FMA + f32 reduce ----
  float l0[8], l1[8];
#pragma unroll
  for (int e = 0; e < 8; ++e) {
    const f4 w = *(const f4*)(gw + e * 1024 + tid * 4);
    l0[e] = o0[0] * w[0] + o0[1] * w[1] + o0[2] * w[2] + o0[3] * w[3];
    l1[e] = o1[0] * w[0] + o1[1] * w[1] + o1[2] * w[2] + o1[3] * w[3];
  }
#pragma unroll
  for (int o = 32; o; o >>= 1)
#pragma unroll
    for (int e = 0; e < 8; ++e) {
      l0[e] += __shfl_xor(l0[e], o);
      l1[e] += __shfl_xor(l1[e], o);
    }
  __shared__ float red2[4][16];
  if (!lane)
#pragma unroll
    for (int e = 0; e < 8; ++e) { red2[wid][e] = l0[e]; red2[wid][8 + e] = l1[e]; }
  __syncthreads();
  if (tid < 2) {                     // tid 0: half 0, tid 1: half 1
    const int h = tid;
    float lg8[8];
#pragma unroll
    for (int e = 0; e < 8; ++e)
      lg8[e] = red2[0][h * 8 + e] + red2[1][h * 8 + e] + red2[2][h * 8 + e]
             + red2[3][h * 8 + e] + gb[e];
    int i0 = 0;
    for (int e = 1; e < 8; ++e) if (lg8[e] > lg8[i0]) i0 = e;
    int i1 = -1;
    for (int e = 0; e < 8; ++e) if (e != i0 && (i1 < 0 || lg8[e] > lg8[i1])) i1 = e;
    const double p = exp((double)lg8[i1] - (double)lg8[i0]);
    const double z = 1.0 + p;
    int* sp = sel + h * CM2 + (size_t)(rowbase + row) * 2;
    float* wp = selw + h * CM2 + (size_t)(rowbase + row) * 2;
    sp[0] = i0; wp[0] = (float)(1.0 / z);
    sp[1] = i1; wp[1] = (float)(p / z);
  }
}

// wave-aggregated per-(half,rank) expert histogram: <=16 atomics per wave
__global__ void count_kernel(const int* __restrict__ sel, int* __restrict__ cnt,
                             const int CM)
{
  const int idx = blockIdx.x * 256 + threadIdx.x;   // h*CM + row
  const bool valid = idx < 2 * CM;
  const int h = (idx / CM) & 1;                     // wave-uniform (CM % 64 == 0)
  const int lane = threadIdx.x & 63;
#pragma unroll
  for (int r = 0; r < 2; ++r) {
    const int e = valid ? sel[idx * 2 + r] : -1;
    const int g = h * 2 + r;
    for (int ee = 0; ee < 8; ++ee) {
      const unsigned long long mask = __ballot(e == ee);
      if (mask && lane == __ffsll((unsigned long long)mask) - 1)
        atomicAdd(&cnt[g * 8 + ee], __popcll(mask));
    }
  }
}

// 128-aligned segment starts + block->expert maps for 4 groups (h,r)
__global__ void prefix_kernel(const int* __restrict__ cnt, int* __restrict__ cursor,
                              int* __restrict__ blkexp, const int NBLK)
{
  const int tid = threadIdx.x;
  for (int i = tid; i < 4 * NBLK; i += 256) blkexp[i] = -1;
  __syncthreads();
  if (tid < 32) {
    const int g = tid >> 3, e = tid & 7;      // g = h*2 + r
    int off = 0;
    for (int j = 0; j < e; ++j) off += ((cnt[g * 8 + j] + 127) >> 7) << 7;
    cursor[g * 8 + e] = off;
    const int nb = (cnt[g * 8 + e] + 127) >> 7;
    for (int b = 0; b < nb; ++b) blkexp[g * NBLK + (off >> 7) + b] = e;
  }
}

// fill per-(half,rank) work-lists via ballot aggregation: one atomic per
// (wave, expert) with popcount; lanes derive slots from mask prefix-pop.
__global__ void scatter_kernel(const int* __restrict__ sel, const float* __restrict__ selw,
                               int* __restrict__ cursor,
                               int* __restrict__ lrow, float* __restrict__ lw,
                               const int CM, const int LCAP)
{
  const int idx = blockIdx.x * 256 + threadIdx.x;   // h*CM + row
  const bool valid = idx < 2 * CM;
  const int h = (idx / CM) & 1;                     // wave-uniform (CM % 64 == 0)
  const int R = valid ? (idx - (idx / CM) * CM) : 0;
  const int lane = threadIdx.x & 63;
#pragma unroll
  for (int r = 0; r < 2; ++r) {
    const int e = valid ? sel[idx * 2 + r] : -1;
    const int g = h * 2 + r;
    int pos = -1;
    for (int ee = 0; ee < 8; ++ee) {
      const unsigned long long mask = __ballot(e == ee);
      if (mask) {
        const int leader = __ffsll((unsigned long long)mask) - 1;
        int base = 0;
        if (lane == leader) base = atomicAdd(&cursor[g * 8 + ee], __popcll(mask));
        base = __shfl(base, leader);
        if (e == ee)
          pos = base + __popcll(mask & ((1ull << lane) - 1ull));
      }
    }
    if (valid) {
      lrow[g * LCAP + pos] = R;
      lw[g * LCAP + pos] = selw[idx * 2 + r];
    }
  }
}

// out[row] = dot(fused_row, reg_w) + reg_b
__global__ __launch_bounds__(256)
void reg_kernel(const float* __restrict__ xf, const float* __restrict__ rw,
                const float* __restrict__ rb, float* __restrict__ out)
{
  const int wid = threadIdx.x >> 6, lane = threadIdx.x & 63;
  const int row = blockIdx.x * 4 + wid;
  const float* xr = xf + (size_t)row * 1024;
  double acc = 0.0;
#pragma unroll
  for (int i = 0; i < 4; ++i) {
    const int f = (lane + 64 * i) * 4;
    const f4 a = *(const f4*)(xr + f);
    const f4 w = *(const f4*)(rw + f);
    acc += (double)a[0] * w[0] + (double)a[1] * w[1] + (double)a[2] * w[2] + (double)a[3] * w[3];
  }
#pragma unroll
  for (int o = 32; o; o >>= 1) acc += __shfl_xor(acc, o);
  if (!lane) out[row] = (float)(acc + (double)rb[0]);
}

// ---------------------------------------------------------------------------

extern "C" void kernel_launch(void* const* d_in, const int* in_sizes, int n_in,
                              void* d_out, int out_size, void* d_ws, size_t ws_size,
                              hipStream_t stream)
{
  (void)in_sizes; (void)n_in; (void)out_size;
  const float* x1    = (const float*)d_in[0];
  const float* x2    = (const float*)d_in[1];
  const float* p1_w  = (const float*)d_in[2];
  const float* p1_b  = (const float*)d_in[3];
  const float* p2_w  = (const float*)d_in[4];
  const float* p2_b  = (const float*)d_in[5];
  const float* m1_w  = (const float*)d_in[6];
  const float* m1_b  = (const float*)d_in[7];
  const float* bn1_g = (const float*)d_in[8];
  const float* bn1_b = (const float*)d_in[9];
  const float* m2_w  = (const float*)d_in[10];
  const float* m2_b  = (const float*)d_in[11];
  const float* bn2_g = (const float*)d_in[12];
  const float* bn2_b = (const float*)d_in[13];
  const float* m3_w  = (const float*)d_in[14];
  const float* m3_b  = (const float*)d_in[15];
  const float* ln_g  = (const float*)d_in[16];
  const float* ln_b  = (const float*)d_in[17];
  const float* ex_w  = (const float*)d_in[18];
  const float* ex_b  = (const float*)d_in[19];
  const float* gate_w= (const float*)d_in[20];
  const float* gate_b= (const float*)d_in[21];
  const float* fus_w = (const float*)d_in[22];
  const float* fus_b = (const float*)d_in[23];
  const float* bnf_g = (const float*)d_in[24];
  const float* bnf_b = (const float*)d_in[25];
  const float* reg_w = (const float*)d_in[26];
  const float* reg_b = (const float*)d_in[27];

  char* ws = (char*)d_ws;
  size_t off = 0;
  auto alloc = [&](size_t bytes) { size_t o = off; off += (bytes + 255) & ~(size_t)255; return o; };

  // ---- fixed region: trunk split weights + folded vectors (~56 MB) ----
  const size_t oWHp1 = alloc((size_t)1048576 * 2), oWLp1 = alloc((size_t)1048576 * 2);
  const size_t oWHp2 = alloc((size_t)1048576 * 2), oWLp2 = alloc((size_t)1048576 * 2);
  const size_t oWHm1 = alloc((size_t)4194304 * 2), oWLm1 = alloc((size_t)4194304 * 2);
  const size_t oWHm2 = alloc((size_t)4194304 * 2), oWLm2 = alloc((size_t)4194304 * 2);
  const size_t oWHm3 = alloc((size_t)4194304 * 2), oWLm3 = alloc((size_t)4194304 * 2);
  const size_t oS1 = alloc(2048 * 4), oT1 = alloc(2048 * 4);
  const size_t oS2 = alloc(2048 * 4), oT2 = alloc(2048 * 4);
  const size_t oFS = alloc(1024 * 4), oFT = alloc(1024 * 4);
  const size_t oCnt = alloc(32 * 4), oCur = alloc(32 * 4);
  const size_t fixedEnd = off;

  // ---- choose outer chunk CM (MoE batch) so everything fits ws_size ----
  int CM = BROWS;
  while (CM > 2048) {
    const int ct = (CM < 4096) ? CM : 4096;
    const size_t nblk = (size_t)CM / 128 + 8;
    const size_t lcap = nblk * 128;
    const size_t need = fixedEnd
                      + 4 * ((size_t)ct * 4096 + 256)   // P planes
                      + 2 * ((size_t)CM * 4096 + 256)   // BFA + BFB
                      + 2 * ((size_t)CM * 16 + 256)     // sel + selw
                      + 2 * (4 * lcap * 4 + 256)        // lrow + lw (4 groups)
                      + (4 * nblk * 4 + 256) + 8192;    // blkexp
    if (ws_size >= need) break;
    CM >>= 1;
  }
  const int CT = (CM < 4096) ? CM : 4096;
  const int NBLK = CM / 128 + 8;
  const int LCAP = NBLK * 128;

  const size_t oP    = alloc(4 * (size_t)CT * 4096);   // trunk planes / ACCb / F32fus
  const size_t oBFA  = alloc((size_t)CM * 4096);
  const size_t oBFB  = alloc((size_t)CM * 4096);
  const size_t oSel  = alloc((size_t)CM * 16);
  const size_t oSelw = alloc((size_t)CM * 16);
  const size_t oLrow = alloc((size_t)4 * LCAP * 4);
  const size_t oLw   = alloc((size_t)4 * LCAP * 4);
  const size_t oBlk  = alloc((size_t)4 * NBLK * 4);

  _Float16* WHp1 = (_Float16*)(ws + oWHp1); _Float16* WLp1 = (_Float16*)(ws + oWLp1);
  _Float16* WHp2 = (_Float16*)(ws + oWHp2); _Float16* WLp2 = (_Float16*)(ws + oWLp2);
  _Float16* WHm1 = (_Float16*)(ws + oWHm1); _Float16* WLm1 = (_Float16*)(ws + oWLm1);
  _Float16* WHm2 = (_Float16*)(ws + oWHm2); _Float16* WLm2 = (_Float16*)(ws + oWLm2);
  _Float16* WHm3 = (_Float16*)(ws + oWHm3); _Float16* WLm3 = (_Float16*)(ws + oWLm3);
  // MoE weights alias the m-layer split weights (converted AFTER the trunk,
  // re-split at the top of each outer iteration):
  __bf16* WBex = (__bf16*)(ws + oWHm1);   // 16 MB over WHm1+WLm1
  __bf16* WBfu = (__bf16*)(ws + oWHm2);   //  4 MB over WHm2
  _Float16* PH0 = (_Float16*)(ws + oP);
  _Float16* PL0 = (_Float16*)(ws + oP + (size_t)CT * 4096);
  _Float16* PH1 = (_Float16*)(ws + oP + 2 * (size_t)CT * 4096);
  _Float16* PL1 = (_Float16*)(ws + oP + 3 * (size_t)CT * 4096);
  float* F32    = (float*)(ws + oP);      // CT x 2048 f32 (planes 0-1)
  __bf16* ACCb  = (__bf16*)(ws + oP);     // CM x 1024 bf16 (rank-0 partial)
  float* F32fus = (float*)(ws + oP);      // CM x 1024 f32 (fus output)
  __bf16* BFA = (__bf16*)(ws + oBFA);     // LN output bf16, CM x 2048
  __bf16* BFB = (__bf16*)(ws + oBFB);     // moe concat bf16, CM x 2048
  int*   sel  = (int*)(ws + oSel);
  float* selw = (float*)(ws + oSelw);
  int*   lrow = (int*)(ws + oLrow);
  float* lw   = (float*)(ws + oLw);
  int*   blkexp = (int*)(ws + oBlk);
  int*   cnt = (int*)(ws + oCnt);
  int*   cur = (int*)(ws + oCur);
  float* s1v = (float*)(ws + oS1); float* t1v = (float*)(ws + oT1);
  float* s2v = (float*)(ws + oS2); float* t2v = (float*)(ws + oT2);
  float* fsv = (float*)(ws + oFS); float* ftv = (float*)(ws + oFT);

  const dim3 T(256);
  // ---- once: fold BN vectors, p-layer splits (never clobbered) ----
  fold_kernel<<<8, T, 0, stream>>>(bn1_g, bn1_b, m1_b, bn2_g, bn2_b, m2_b,
                                   bnf_g, bnf_b, fus_b, s1v, t1v, s2v, t2v, fsv, ftv);
  split_w<<<1024, T, 0, stream>>>(p1_w, WHp1, WLp1, 1048576);
  split_w<<<1024, T, 0, stream>>>(p2_w, WHp2, WLp2, 1048576);

  const dim3 GP(CT / 128, 8, 2), GT16(CT / 128, 16, 1), GM(NBLK, 8), GF(CM / 128, 8);
  for (int m0 = 0; m0 < BROWS; m0 += CM) {
    // m-layer split weights (region shared with WBex/WBfu -> re-split)
    split_w<<<4096, T, 0, stream>>>(m1_w, WHm1, WLm1, 4194304);
    split_w<<<4096, T, 0, stream>>>(m2_w, WHm2, WLm2, 4194304);
    split_w<<<4096, T, 0, stream>>>(m3_w, WHm3, WLm3, 4194304);

    // ---- trunk, inner-chunked at CT ----
    for (int r0 = 0; r0 < CM; r0 += CT) {
      const float* x1c = x1 + (size_t)(m0 + r0) * 1024;
      const float* x2c = x2 + (size_t)(m0 + r0) * 1024;
      prep_x<<<CT * 2, T, 0, stream>>>(x1c, x2c, PH0, PL0);
      // p1 + p2 merged (z selects weight set; A/C offset by 1024 cols)
      gemm_split<0><<<GP, T, 0, stream>>>(PH0, PL0, WHp1, WLp1, WHp2, WLp2,
                                          2048, 1024, 1024,
                                          PH1, PL1, nullptr, 2048,
                                          p1_b, nullptr, p2_b, 1024);
      gemm_split<1><<<GT16, T, 0, stream>>>(PH1, PL1, WHm1, WLm1, WHm1, WLm1,
                                            2048, 2048, 2048,
                                            PH0, PL0, nullptr, 2048,
                                            s1v, t1v, s1v, 0);
      gemm_split<1><<<GT16, T, 0, stream>>>(PH0, PL0, WHm2, WLm2, WHm2, WLm2,
                                            2048, 2048, 2048,
                                            PH1, PL1, nullptr, 2048,
                                            s2v, t2v, s2v, 0);
      gemm_split<2><<<GT16, T, 0, stream>>>(PH1, PL1, WHm3, WLm3, WHm3, WLm3,
                                            2048, 2048, 2048,
                                            nullptr, nullptr, F32, 2048,
                                            m3_b, nullptr, m3_b, 0);
      // LN + fused gate (writes BFA bf16 + sel/selw; no F32 writeback)
      ln_gate_kernel<<<CT, T, 0, stream>>>(F32, BFA + (size_t)r0 * 2048,
                                           ln_g, ln_b, gate_w, gate_b,
                                           sel, selw, r0, CM * 2);
    }

    // ---- MoE weights (clobber m-layer splits now that trunk is done) ----
    cvt_bf<<<8192, T, 0, stream>>>(ex_w, WBex, 8388608);
    cvt_bf<<<2048, T, 0, stream>>>(fus_w, WBfu, 2097152);

    // ---- full-batch MoE (ballot-aggregated bucketing) ----
    hipMemsetAsync(cnt, 0, 32 * 4, stream);
    count_kernel<<<(2 * CM + 255) / 256, T, 0, stream>>>(sel, cnt, CM);
    prefix_kernel<<<1, T, 0, stream>>>(cnt, cur, blkexp, NBLK);
    hipMemsetAsync(lrow, 0xFF, (size_t)4 * LCAP * 4, stream);
    scatter_kernel<<<(2 * CM + 255) / 256, T, 0, stream>>>(sel, selw, cur, lrow, lw, CM, LCAP);
    for (int h = 0; h < 2; ++h) {
      const int g0 = h * 2, g1 = h * 2 + 1;
      gemm_moe<0><<<GM, T, 0, stream>>>(BFA + h * 1024, WBex,
                                        lrow + (size_t)g0 * LCAP, lw + (size_t)g0 * LCAP,
                                        blkexp + g0 * NBLK, ex_b, ACCb, nullptr);
      gemm_moe<1><<<GM, T, 0, stream>>>(BFA + h * 1024, WBex,
                                        lrow + (size_t)g1 * LCAP, lw + (size_t)g1 * LCAP,
                                        blkexp + g1 * NBLK, ex_b, ACCb, BFB + h * 1024);
    }

    // ---- fus + reg on the full outer chunk ----
    gemm_fus<<<GF, T, 0, stream>>>(BFB, WBfu, 2048, 2048, 2048, F32fus, 1024, fsv, ftv);
    reg_kernel<<<CM / 4, T, 0, stream>>>(F32fus, reg_w, reg_b, (float*)d_out + m0);
  }
}

// Round 10
// 1802.699 us; speedup vs baseline: 1.1428x; 1.0080x over previous
//
#include <hip/hip_runtime.h>
#include <stdint.h>
#include <math.h>

#define BROWS 16384

typedef _Float16 h8 __attribute__((ext_vector_type(8)));
typedef _Float16 h4 __attribute__((ext_vector_type(4)));
typedef __bf16   b8 __attribute__((ext_vector_type(8)));
typedef __bf16   b4 __attribute__((ext_vector_type(4)));
typedef float    f4 __attribute__((ext_vector_type(4)));

typedef __attribute__((address_space(3))) char       lds_char;
typedef __attribute__((address_space(1))) const char gbl_char;

// async global->LDS, 16B per lane; LDS dest = wave-uniform base + lane*16
// (global SOURCE address is per-lane -> usable as gather AND as pre-swizzle)
__device__ __forceinline__ void gload16(const void* g, void* l) {
  __builtin_amdgcn_global_load_lds((const gbl_char*)(uintptr_t)g,
                                   (lds_char*)(uintptr_t)l, 16, 0, 0);
}

// BK=64 tile: [128 rows][64 halfs] = 16KB/plane, row stride 128B.
// LDS(row, cb) holds global colblock cb^(row&7)  [staged via pre-swizzled
// per-lane global source colbyte ((l&7)^(l>>3))*16, linear LDS dest].
// 16x16x32 fragment read at colblock ((ks*4 + (lane>>4)) ^ (lane&7)):
// measured conflict-free (round 7: SQ_LDS_BANK_CONFLICT == 0).

// ---------------------------------------------------------------------------
// fp16 2-term split GEMM:  C = A @ W^T (+epilogue), A = Ah + Al/2048,
// W = Wh + Wl/2048, row-major, K contiguous. blockIdx.z selects second
// weight set / bias and offsets A,C by zoff (merged p1+p2 launch).
// EPI 0: y += v0[col]; write split planes Ch/Cl          (p1, p2)
// EPI 1: y = relu(y*v0[col] + v1[col]); write Ch/Cl      (m1, m2)
// EPI 2: Cf = y + v0[col]  (f32)                          (m3)
// ---------------------------------------------------------------------------
template<int EPI>
__global__ __launch_bounds__(256, 2)
void gemm_split(const _Float16* __restrict__ Ah, const _Float16* __restrict__ Al,
                const _Float16* __restrict__ Wh, const _Float16* __restrict__ Wl,
                const _Float16* __restrict__ WhB, const _Float16* __restrict__ WlB,
                const int lda, const int ldw, const int K,
                _Float16* __restrict__ Ch, _Float16* __restrict__ Cl,
                float* __restrict__ Cf, const int ldc,
                const float* __restrict__ v0, const float* __restrict__ v1,
                const float* __restrict__ v0B, const int zoff)
{
  __shared__ char smem[65536];
  char* const sAh = smem;
  char* const sAl = smem + 16384;
  char* const sWh = smem + 32768;
  char* const sWl = smem + 49152;

  if (blockIdx.z) {               // wave-uniform select (p2 of the merged pair)
    Wh = WhB; Wl = WlB; v0 = v0B;
    Ah += zoff; Al += zoff; Ch += zoff; Cl += zoff;
  }

  const int tid  = threadIdx.x;
  const int wid  = tid >> 6, lane = tid & 63;
  const int bm = blockIdx.x, bn = blockIdx.y;
  const int wr = wid >> 1, wc = wid & 1;          // 2x2 waves, 64x64 each
  const int sr  = lane >> 3;                      // staging row-in-8
  const int scb = ((lane & 7) ^ sr) * 16;         // pre-swizzled source colbyte
  const int fr  = lane & 15;                      // fragment row
  const int sw0 = ((lane >> 4) ^ (lane & 7)) * 16;        // read swz, ks=0
  const int sw1 = ((4 + (lane >> 4)) ^ (lane & 7)) * 16;  // read swz, ks=1

  f4 accA[4][4] = {};
  f4 accB[4][4] = {};

  const size_t arow0 = (size_t)bm * 128;
  const size_t wrow0 = (size_t)bn * 128;

  for (int k0 = 0; k0 < K; k0 += 64) {
    __syncthreads();
#pragma unroll
    for (int i = 0; i < 4; ++i) {
      const int rb = wid * 32 + i * 8;
      const size_t ga = (arow0 + rb + sr) * (size_t)lda + k0;
      const size_t gw = (wrow0 + rb + sr) * (size_t)ldw + k0;
      const int lo = rb * 128;                    // wave-uniform LDS base
      gload16((const char*)(Ah + ga) + scb, sAh + lo);
      gload16((const char*)(Al + ga) + scb, sAl + lo);
      gload16((const char*)(Wh + gw) + scb, sWh + lo);
      gload16((const char*)(Wl + gw) + scb, sWl + lo);
    }
    __syncthreads();

#pragma unroll
    for (int ks = 0; ks < 2; ++ks) {
      const int sw = ks ? sw1 : sw0;
      h8 ah[4], al[4], bh[4], bl[4];
#pragma unroll
      for (int mi = 0; mi < 4; ++mi) {
        const int r = (wr * 64 + mi * 16 + fr) * 128 + sw;
        ah[mi] = *(const h8*)(sAh + r);
        al[mi] = *(const h8*)(sAl + r);
      }
#pragma unroll
      for (int ni = 0; ni < 4; ++ni) {
        const int r = (wc * 64 + ni * 16 + fr) * 128 + sw;
        bh[ni] = *(const h8*)(sWh + r);
        bl[ni] = *(const h8*)(sWl + r);
      }
#pragma unroll
      for (int mi = 0; mi < 4; ++mi)
#pragma unroll
        for (int ni = 0; ni < 4; ++ni) {
          accA[mi][ni] = __builtin_amdgcn_mfma_f32_16x16x32_f16(ah[mi], bh[ni], accA[mi][ni], 0, 0, 0);
          accB[mi][ni] = __builtin_amdgcn_mfma_f32_16x16x32_f16(ah[mi], bl[ni], accB[mi][ni], 0, 0, 0);
          accB[mi][ni] = __builtin_amdgcn_mfma_f32_16x16x32_f16(al[mi], bh[ni], accB[mi][ni], 0, 0, 0);
        }
    }
  }

  const int rg = (lane >> 4) * 4;                 // C/D: col=lane&15, row=(lane>>4)*4+j
#pragma unroll
  for (int mi = 0; mi < 4; ++mi)
#pragma unroll
    for (int ni = 0; ni < 4; ++ni) {
      const int gcol = bn * 128 + wc * 64 + ni * 16 + fr;
      const float a0 = v0[gcol];
      const float a1 = (EPI == 1) ? v1[gcol] : 0.f;
#pragma unroll
      for (int j = 0; j < 4; ++j) {
        const size_t grow = arow0 + wr * 64 + mi * 16 + rg + j;
        float y = accA[mi][ni][j] + accB[mi][ni][j] * (1.f / 2048.f);
        const size_t off = grow * (size_t)ldc + gcol;
        if constexpr (EPI == 0) {
          y += a0;
          const _Float16 hh = (_Float16)y;
          Ch[off] = hh;
          Cl[off] = (_Float16)((y - (float)hh) * 2048.f);
        } else if constexpr (EPI == 1) {
          y = fmaxf(fmaf(y, a0, a1), 0.f);
          const _Float16 hh = (_Float16)y;
          Ch[off] = hh;
          Cl[off] = (_Float16)((y - (float)hh) * 2048.f);
        } else {
          Cf[off] = y + a0;
        }
      }
    }
}

// ---------------------------------------------------------------------------
// bf16 GEMM for the fus layer: Cf = (A @ W^T)*v0[col] + v1[col]   (BK=64)
// ---------------------------------------------------------------------------
__global__ __launch_bounds__(256, 2)
void gemm_fus(const __bf16* __restrict__ A, const __bf16* __restrict__ W,
              const int lda, const int ldw, const int K,
              float* __restrict__ Cf, const int ldc,
              const float* __restrict__ v0, const float* __restrict__ v1)
{
  __shared__ char smem[32768];
  char* const sA = smem;
  char* const sW = smem + 16384;

  const int tid  = threadIdx.x;
  const int wid  = tid >> 6, lane = tid & 63;
  const int bm = blockIdx.x, bn = blockIdx.y;
  const int wr = wid >> 1, wc = wid & 1;
  const int sr  = lane >> 3;
  const int scb = ((lane & 7) ^ sr) * 16;
  const int fr  = lane & 15;
  const int sw0 = ((lane >> 4) ^ (lane & 7)) * 16;
  const int sw1 = ((4 + (lane >> 4)) ^ (lane & 7)) * 16;

  f4 acc[4][4] = {};

  const size_t arow0 = (size_t)bm * 128;
  const size_t wrow0 = (size_t)bn * 128;

  for (int k0 = 0; k0 < K; k0 += 64) {
    __syncthreads();
#pragma unroll
    for (int i = 0; i < 4; ++i) {
      const int rb = wid * 32 + i * 8;
      const size_t ga = (arow0 + rb + sr) * (size_t)lda + k0;
      const size_t gw = (wrow0 + rb + sr) * (size_t)ldw + k0;
      const int lo = rb * 128;
      gload16((const char*)(A + ga) + scb, sA + lo);
      gload16((const char*)(W + gw) + scb, sW + lo);
    }
    __syncthreads();

#pragma unroll
    for (int ks = 0; ks < 2; ++ks) {
      const int sw = ks ? sw1 : sw0;
      b8 av[4], bv[4];
#pragma unroll
      for (int mi = 0; mi < 4; ++mi)
        av[mi] = *(const b8*)(sA + (wr * 64 + mi * 16 + fr) * 128 + sw);
#pragma unroll
      for (int ni = 0; ni < 4; ++ni)
        bv[ni] = *(const b8*)(sW + (wc * 64 + ni * 16 + fr) * 128 + sw);
#pragma unroll
      for (int mi = 0; mi < 4; ++mi)
#pragma unroll
        for (int ni = 0; ni < 4; ++ni)
          acc[mi][ni] = __builtin_amdgcn_mfma_f32_16x16x32_bf16(av[mi], bv[ni], acc[mi][ni], 0, 0, 0);
    }
  }

  const int rg = (lane >> 4) * 4;
#pragma unroll
  for (int mi = 0; mi < 4; ++mi)
#pragma unroll
    for (int j = 0; j < 4; ++j) {
      const size_t grow = arow0 + wr * 64 + mi * 16 + rg + j;
#pragma unroll
      for (int ni = 0; ni < 4; ++ni) {
        const int gcol = bn * 128 + wc * 64 + ni * 16 + fr;
        Cf[grow * (size_t)ldc + gcol] = fmaf(acc[mi][ni][j], v0[gcol], v1[gcol]);
      }
    }
}

// ---------------------------------------------------------------------------
// gathered per-(half,rank) expert GEMM (BK=64). Block bx: 128 worklist rows,
// all expert blkexp[bx]; by = 128-col tile. A rows gathered via per-lane
// global_load_lds source addresses (pre-swizzled cols).
// bx is XCD-chunk swizzled (bijective, NBLK % 8 == 0): consecutive worklist
// segments (same expert -> same W tiles) land on the SAME XCD so the expert
// weight by-tile stays L2-resident instead of being refetched from L3 by all
// 8 XCDs.
// PASS 0 (rank 0): ACCb[row][col] = bf16( w * ((A[row]@We^T)[col] + be[col]) )
// PASS 1 (rank 1): BFBh[row][col] = bf16( ACCb[row][col] + w * (...) )
// Row-unique writers per pass -> bit-deterministic regardless of scatter order.
// ---------------------------------------------------------------------------
template<int PASS>
__global__ __launch_bounds__(256, 2)
void gemm_moe(const __bf16* __restrict__ A,      // BFA + h*1024, lda 2048
              const __bf16* __restrict__ Wall,   // 8 x (1024x1024) bf16
              const int* __restrict__ lrow, const float* __restrict__ lw,
              const int* __restrict__ blkexp,
              const float* __restrict__ eb,      // ex_b (8x1024)
              __bf16* __restrict__ ACCb,         // CM x 1024 bf16
              __bf16* __restrict__ BFBh)         // BFB + h*1024, ld 2048
{
  // XCD-chunked bijective swizzle: xcd = dispatch bx % 8 (by*NBLK % 8 == 0),
  // each xcd gets a contiguous work-index chunk.
  const int nb = gridDim.x;                       // NBLK, divisible by 8
  const int bx = (blockIdx.x & 7) * (nb >> 3) + (blockIdx.x >> 3);
  const int by = blockIdx.y;
  const int e = blkexp[bx];
  if (e < 0) return;                              // fully-pad block

  __shared__ char smem[32768];
  __shared__ int   slrow[128];
  __shared__ float slw[128];
  char* const sA = smem;
  char* const sW = smem + 16384;

  const int tid  = threadIdx.x;
  const int wid  = tid >> 6, lane = tid & 63;
  if (tid < 128) { slrow[tid] = lrow[bx * 128 + tid]; slw[tid] = lw[bx * 128 + tid]; }
  __syncthreads();

  const __bf16* W = Wall + (size_t)e * 1048576 + (size_t)by * 131072;

  const int wr = wid >> 1, wc = wid & 1;
  const int sr  = lane >> 3;
  const int scb = ((lane & 7) ^ sr) * 16;
  const int fr  = lane & 15;
  const int sw0 = ((lane >> 4) ^ (lane & 7)) * 16;
  const int sw1 = ((4 + (lane >> 4)) ^ (lane & 7)) * 16;

  // per-lane gathered A base pointers (4 staging loads per wave)
  const char* abase[4];
#pragma unroll
  for (int i = 0; i < 4; ++i) {
    int s = slrow[wid * 32 + i * 8 + sr];
    if (s < 0) s = 0;
    abase[i] = (const char*)(A + (size_t)s * 2048) + scb;
  }

  f4 acc[4][4] = {};

  for (int k0 = 0; k0 < 1024; k0 += 64) {
    __syncthreads();
#pragma unroll
    for (int i = 0; i < 4; ++i) {
      const int rb = wid * 32 + i * 8;
      const int lo = rb * 128;
      gload16(abase[i] + (size_t)k0 * 2, sA + lo);
      gload16((const char*)(W + (size_t)(rb + sr) * 1024 + k0) + scb, sW + lo);
    }
    __syncthreads();

#pragma unroll
    for (int ks = 0; ks < 2; ++ks) {
      const int sw = ks ? sw1 : sw0;
      b8 av[4], bv[4];
#pragma unroll
      for (int mi = 0; mi < 4; ++mi)
        av[mi] = *(const b8*)(sA + (wr * 64 + mi * 16 + fr) * 128 + sw);
#pragma unroll
      for (int ni = 0; ni < 4; ++ni)
        bv[ni] = *(const b8*)(sW + (wc * 64 + ni * 16 + fr) * 128 + sw);
#pragma unroll
      for (int mi = 0; mi < 4; ++mi)
#pragma unroll
        for (int ni = 0; ni < 4; ++ni)
          acc[mi][ni] = __builtin_amdgcn_mfma_f32_16x16x32_bf16(av[mi], bv[ni], acc[mi][ni], 0, 0, 0);
    }
  }

  const int rg = (lane >> 4) * 4;
  const float* ebp = eb + (size_t)e * 1024;
#pragma unroll
  for (int mi = 0; mi < 4; ++mi)
#pragma unroll
    for (int j = 0; j < 4; ++j) {
      const int local = wr * 64 + mi * 16 + rg + j;
      const int R = slrow[local];
      if (R < 0) continue;
      const float w = slw[local];
#pragma unroll
      for (int ni = 0; ni < 4; ++ni) {
        const int gcol = by * 128 + wc * 64 + ni * 16 + fr;
        const float v = w * (acc[mi][ni][j] + ebp[gcol]);
        if constexpr (PASS == 0) {
          ACCb[(size_t)R * 1024 + gcol] = (__bf16)v;
        } else {
          BFBh[(size_t)R * 2048 + gcol] = (__bf16)((float)ACCb[(size_t)R * 1024 + gcol] + v);
        }
      }
    }
}

// --------------------------- prep / elementwise ----------------------------

__global__ void split_w(const float* __restrict__ src, _Float16* __restrict__ dh,
                        _Float16* __restrict__ dl, const size_t n)
{
  const size_t i = ((size_t)blockIdx.x * 256 + threadIdx.x) * 4;
  if (i >= n) return;
  const f4 v = *(const f4*)(src + i);
  h4 hh, ll;
#pragma unroll
  for (int j = 0; j < 4; ++j) {
    const _Float16 h = (_Float16)v[j];
    hh[j] = h;
    ll[j] = (_Float16)((v[j] - (float)h) * 2048.f);
  }
  *(h4*)(dh + i) = hh;
  *(h4*)(dl + i) = ll;
}

__global__ void cvt_bf(const float* __restrict__ src, __bf16* __restrict__ dst, const size_t n)
{
  const size_t i = ((size_t)blockIdx.x * 256 + threadIdx.x) * 4;
  if (i >= n) return;
  const f4 v = *(const f4*)(src + i);
  b4 o;
#pragma unroll
  for (int j = 0; j < 4; ++j) o[j] = (__bf16)v[j];
  *(b4*)(dst + i) = o;
}

// x1 -> cols [0,1024), x2 -> cols [1024,2048) of split planes (lda 2048).
// 8 floats / thread (c block of 8 never straddles the 1024 boundary).
__global__ void prep_x(const float* __restrict__ x1, const float* __restrict__ x2,
                       _Float16* __restrict__ ph, _Float16* __restrict__ pl)
{
  const size_t i = ((size_t)blockIdx.x * 256 + threadIdx.x) * 8;
  const int b = (int)(i >> 11);
  const int c = (int)(i & 2047);
  const float* s = (c < 1024) ? (x1 + (size_t)b * 1024 + c)
                              : (x2 + (size_t)b * 1024 + (c - 1024));
  const f4 v0 = *(const f4*)s;
  const f4 v1 = *(const f4*)(s + 4);
  h8 hh, ll;
#pragma unroll
  for (int j = 0; j < 4; ++j) {
    const _Float16 h0 = (_Float16)v0[j];
    hh[j] = h0;
    ll[j] = (_Float16)((v0[j] - (float)h0) * 2048.f);
    const _Float16 h1 = (_Float16)v1[j];
    hh[4 + j] = h1;
    ll[4 + j] = (_Float16)((v1[j] - (float)h1) * 2048.f);
  }
  *(h8*)(ph + i) = hh;
  *(h8*)(pl + i) = ll;
}

// fold BN-eval into per-col scale/shift: s = g/sqrt(1+eps), t = mb*s + b
__global__ void fold_kernel(const float* g1, const float* b1, const float* mb1,
                            const float* g2, const float* b2, const float* mb2,
                            const float* gf, const float* bf, const float* fb,
                            float* s1, float* t1, float* s2, float* t2,
                            float* fs, float* ft)
{
  const int t = blockIdx.x * 256 + threadIdx.x;
  const float inv = (float)(1.0 / sqrt(1.0 + 1.0e-5));
  if (t < 2048) {
    float a = g1[t] * inv; s1[t] = a; t1[t] = mb1[t] * a + b1[t];
    float c = g2[t] * inv; s2[t] = c; t2[t] = mb2[t] * c + b2[t];
  }
  if (t < 1024) {
    float a = gf[t] * inv; fs[t] = a; ft[t] = fb[t] * a + bf[t];
  }
}

// LayerNorm over 2048 cols -> bf16 out; FUSED gate (top2 softmax -> sel/selw).
// LN stats in f64 (guards logit precision); gate dots in f32 (error ~3e-6
// vs min top-2 gap ~1e-5 -- validated rounds 8/9, identical absmax).
__global__ __launch_bounds__(256)
void ln_gate_kernel(const float* __restrict__ xf, __bf16* __restrict__ xb,
                    const float* __restrict__ lg, const float* __restrict__ lb,
                    const float* __restrict__ gw, const float* __restrict__ gb,
                    int* __restrict__ sel, float* __restrict__ selw,
                    const int rowbase, const int CM2)
{
  const int row = blockIdx.x;
  const float* xr = xf + (size_t)row * 2048;
  const int tid = threadIdx.x;
  const int wid = tid >> 6, lane = tid & 63;
  const f4 v0 = *(const f4*)(xr + tid * 4);
  const f4 v1 = *(const f4*)(xr + 1024 + tid * 4);
  double s = 0.0, ss = 0.0;
#pragma unroll
  for (int j = 0; j < 4; ++j) {
    s  += (double)v0[j] + (double)v1[j];
    ss += (double)v0[j] * v0[j] + (double)v1[j] * v1[j];
  }
#pragma unroll
  for (int o = 32; o; o >>= 1) { s += __shfl_xor(s, o); ss += __shfl_xor(ss, o); }
  __shared__ double red[8];
  if (!lane) { red[wid] = s; red[4 + wid] = ss; }
  __syncthreads();
  const double S  = red[0] + red[1] + red[2] + red[3];
  const double SS = red[4] + red[5] + red[6] + red[7];
  const double mu = S * (1.0 / 2048.0);
  const double var = SS * (1.0 / 2048.0) - mu * mu;
  const float inv = (float)(1.0 / sqrt(var + 1.0e-5));
  const float muf = (float)mu;
  f4 o0, o1;
  b4 q0, q1;
#pragma unroll
  for (int j = 0; j < 4; ++j) {
    const int c0 = tid * 4 + j, c1 = 1024 + tid * 4 + j;
    o0[j] = (v0[j] - muf) * inv * lg[c0] + lb[c0];
    o1[j] = (v1[j] - muf) * inv * lg[c1] + lb[c1];
    q0[j] = (__bf16)o0[j];
    q1[j] = (__bf16)o1[j];
  }
  *(b4*)(xb + (size_t)row * 2048 + tid * 4) = q0;
  *(b4*)(xb + (size_t)row * 2048 + 1024 + tid * 4) = q1;

  // ---- fused gate: 16 dots (2 halves x 8 experts), f32 FMA + f32 reduce ----
  float l0[8], l1[8];
#pragma unroll
  for (int e = 0; e < 8; ++e) {
    const f4 w = *(const f4*)(gw + e * 1024 + tid * 4);
    l0[e] = o0[0] * w[0] + o0[1] * w[1] + o0[2] * w[2] + o0[3] * w[3];
    l1[e] = o1[0] * w[0] + o1[1] * w[1] + o1[2] * w[2] + o1[3] * w[3];
  }
#pragma unroll
  for (int o = 32; o; o >>= 1)
#pragma unroll
    for (int e = 0; e < 8; ++e) {
      l0[e] += __shfl_xor(l0[e], o);
      l1[e] += __shfl_xor(l1[e], o);
    }
  __shared__ float red2[4][16];
  if (!lane)
#pragma unroll
    for (int e = 0; e < 8; ++e) { red2[wid][e] = l0[e]; red2[wid][8 + e] = l1[e]; }
  __syncthreads();
  if (tid < 2) {                     // tid 0: half 0, tid 1: half 1
    const int h = tid;
    float lg8[8];
#pragma unroll
    for (int e = 0; e < 8; ++e)
      lg8[e] = red2[0][h * 8 + e] + red2[1][h * 8 + e] + red2[2][h * 8 + e]
             + red2[3][h * 8 + e] + gb[e];
    int i0 = 0;
    for (int e = 1; e < 8; ++e) if (lg8[e] > lg8[i0]) i0 = e;
    int i1 = -1;
    for (int e = 0; e < 8; ++e) if (e != i0 && (i1 < 0 || lg8[e] > lg8[i1])) i1 = e;
    const double p = exp((double)lg8[i1] - (double)lg8[i0]);
    const double z = 1.0 + p;
    int* sp = sel + h * CM2 + (size_t)(rowbase + row) * 2;
    float* wp = selw + h * CM2 + (size_t)(rowbase + row) * 2;
    sp[0] = i0; wp[0] = (float)(1.0 / z);
    sp[1] = i1; wp[1] = (float)(p / z);
  }
}

// wave-aggregated per-(half,rank) expert histogram: <=16 atomics per wave
__global__ void count_kernel(const int* __restrict__ sel, int* __restrict__ cnt,
                             const int CM)
{
  const int idx = blockIdx.x * 256 + threadIdx.x;   // h*CM + row
  const bool valid = idx < 2 * CM;
  const int h = (idx / CM) & 1;                     // wave-uniform (CM % 64 == 0)
  const int lane = threadIdx.x & 63;
#pragma unroll
  for (int r = 0; r < 2; ++r) {
    const int e = valid ? sel[idx * 2 + r] : -1;
    const int g = h * 2 + r;
    for (int ee = 0; ee < 8; ++ee) {
      const unsigned long long mask = __ballot(e == ee);
      if (mask && lane == __ffsll((unsigned long long)mask) - 1)
        atomicAdd(&cnt[g * 8 + ee], __popcll(mask));
    }
  }
}

// 128-aligned segment starts + block->expert maps for 4 groups (h,r)
__global__ void prefix_kernel(const int* __restrict__ cnt, int* __restrict__ cursor,
                              int* __restrict__ blkexp, const int NBLK)
{
  const int tid = threadIdx.x;
  for (int i = tid; i < 4 * NBLK; i += 256) blkexp[i] = -1;
  __syncthreads();
  if (tid < 32) {
    const int g = tid >> 3, e = tid & 7;      // g = h*2 + r
    int off = 0;
    for (int j = 0; j < e; ++j) off += ((cnt[g * 8 + j] + 127) >> 7) << 7;
    cursor[g * 8 + e] = off;
    const int nb = (cnt[g * 8 + e] + 127) >> 7;
    for (int b = 0; b < nb; ++b) blkexp[g * NBLK + (off >> 7) + b] = e;
  }
}

// fill per-(half,rank) work-lists via ballot aggregation: one atomic per
// (wave, expert) with popcount; lanes derive slots from mask prefix-pop.
__global__ void scatter_kernel(const int* __restrict__ sel, const float* __restrict__ selw,
                               int* __restrict__ cursor,
                               int* __restrict__ lrow, float* __restrict__ lw,
                               const int CM, const int LCAP)
{
  const int idx = blockIdx.x * 256 + threadIdx.x;   // h*CM + row
  const bool valid = idx < 2 * CM;
  const int h = (idx / CM) & 1;                     // wave-uniform (CM % 64 == 0)
  const int R = valid ? (idx - (idx / CM) * CM) : 0;
  const int lane = threadIdx.x & 63;
#pragma unroll
  for (int r = 0; r < 2; ++r) {
    const int e = valid ? sel[idx * 2 + r] : -1;
    const int g = h * 2 + r;
    int pos = -1;
    for (int ee = 0; ee < 8; ++ee) {
      const unsigned long long mask = __ballot(e == ee);
      if (mask) {
        const int leader = __ffsll((unsigned long long)mask) - 1;
        int base = 0;
        if (lane == leader) base = atomicAdd(&cursor[g * 8 + ee], __popcll(mask));
        base = __shfl(base, leader);
        if (e == ee)
          pos = base + __popcll(mask & ((1ull << lane) - 1ull));
      }
    }
    if (valid) {
      lrow[g * LCAP + pos] = R;
      lw[g * LCAP + pos] = selw[idx * 2 + r];
    }
  }
}

// out[row] = dot(fused_row, reg_w) + reg_b
__global__ __launch_bounds__(256)
void reg_kernel(const float* __restrict__ xf, const float* __restrict__ rw,
                const float* __restrict__ rb, float* __restrict__ out)
{
  const int wid = threadIdx.x >> 6, lane = threadIdx.x & 63;
  const int row = blockIdx.x * 4 + wid;
  const float* xr = xf + (size_t)row * 1024;
  double acc = 0.0;
#pragma unroll
  for (int i = 0; i < 4; ++i) {
    const int f = (lane + 64 * i) * 4;
    const f4 a = *(const f4*)(xr + f);
    const f4 w = *(const f4*)(rw + f);
    acc += (double)a[0] * w[0] + (double)a[1] * w[1] + (double)a[2] * w[2] + (double)a[3] * w[3];
  }
#pragma unroll
  for (int o = 32; o; o >>= 1) acc += __shfl_xor(acc, o);
  if (!lane) out[row] = (float)(acc + (double)rb[0]);
}

// ---------------------------------------------------------------------------

extern "C" void kernel_launch(void* const* d_in, const int* in_sizes, int n_in,
                              void* d_out, int out_size, void* d_ws, size_t ws_size,
                              hipStream_t stream)
{
  (void)in_sizes; (void)n_in; (void)out_size;
  const float* x1    = (const float*)d_in[0];
  const float* x2    = (const float*)d_in[1];
  const float* p1_w  = (const float*)d_in[2];
  const float* p1_b  = (const float*)d_in[3];
  const float* p2_w  = (const float*)d_in[4];
  const float* p2_b  = (const float*)d_in[5];
  const float* m1_w  = (const float*)d_in[6];
  const float* m1_b  = (const float*)d_in[7];
  const float* bn1_g = (const float*)d_in[8];
  const float* bn1_b = (const float*)d_in[9];
  const float* m2_w  = (const float*)d_in[10];
  const float* m2_b  = (const float*)d_in[11];
  const float* bn2_g = (const float*)d_in[12];
  const float* bn2_b = (const float*)d_in[13];
  const float* m3_w  = (const float*)d_in[14];
  const float* m3_b  = (const float*)d_in[15];
  const float* ln_g  = (const float*)d_in[16];
  const float* ln_b  = (const float*)d_in[17];
  const float* ex_w  = (const float*)d_in[18];
  const float* ex_b  = (const float*)d_in[19];
  const float* gate_w= (const float*)d_in[20];
  const float* gate_b= (const float*)d_in[21];
  const float* fus_w = (const float*)d_in[22];
  const float* fus_b = (const float*)d_in[23];
  const float* bnf_g = (const float*)d_in[24];
  const float* bnf_b = (const float*)d_in[25];
  const float* reg_w = (const float*)d_in[26];
  const float* reg_b = (const float*)d_in[27];

  char* ws = (char*)d_ws;
  size_t off = 0;
  auto alloc = [&](size_t bytes) { size_t o = off; off += (bytes + 255) & ~(size_t)255; return o; };

  // ---- fixed region: trunk split weights + folded vectors (~56 MB) ----
  const size_t oWHp1 = alloc((size_t)1048576 * 2), oWLp1 = alloc((size_t)1048576 * 2);
  const size_t oWHp2 = alloc((size_t)1048576 * 2), oWLp2 = alloc((size_t)1048576 * 2);
  const size_t oWHm1 = alloc((size_t)4194304 * 2), oWLm1 = alloc((size_t)4194304 * 2);
  const size_t oWHm2 = alloc((size_t)4194304 * 2), oWLm2 = alloc((size_t)4194304 * 2);
  const size_t oWHm3 = alloc((size_t)4194304 * 2), oWLm3 = alloc((size_t)4194304 * 2);
  const size_t oS1 = alloc(2048 * 4), oT1 = alloc(2048 * 4);
  const size_t oS2 = alloc(2048 * 4), oT2 = alloc(2048 * 4);
  const size_t oFS = alloc(1024 * 4), oFT = alloc(1024 * 4);
  const size_t oCnt = alloc(32 * 4), oCur = alloc(32 * 4);
  const size_t fixedEnd = off;

  // ---- choose outer chunk CM (MoE batch) so everything fits ws_size ----
  int CM = BROWS;
  while (CM > 2048) {
    const int ct = (CM < 4096) ? CM : 4096;
    const size_t nblk = (size_t)CM / 128 + 8;
    const size_t lcap = nblk * 128;
    const size_t need = fixedEnd
                      + 4 * ((size_t)ct * 4096 + 256)   // P planes
                      + 2 * ((size_t)CM * 4096 + 256)   // BFA + BFB
                      + 2 * ((size_t)CM * 16 + 256)     // sel + selw
                      + 2 * (4 * lcap * 4 + 256)        // lrow + lw (4 groups)
                      + (4 * nblk * 4 + 256) + 8192;    // blkexp
    if (ws_size >= need) break;
    CM >>= 1;
  }
  const int CT = (CM < 4096) ? CM : 4096;
  const int NBLK = CM / 128 + 8;                   // divisible by 8 for CM>=1024
  const int LCAP = NBLK * 128;

  const size_t oP    = alloc(4 * (size_t)CT * 4096);   // trunk planes / ACCb / F32fus
  const size_t oBFA  = alloc((size_t)CM * 4096);
  const size_t oBFB  = alloc((size_t)CM * 4096);
  const size_t oSel  = alloc((size_t)CM * 16);
  const size_t oSelw = alloc((size_t)CM * 16);
  const size_t oLrow = alloc((size_t)4 * LCAP * 4);
  const size_t oLw   = alloc((size_t)4 * LCAP * 4);
  const size_t oBlk  = alloc((size_t)4 * NBLK * 4);

  _Float16* WHp1 = (_Float16*)(ws + oWHp1); _Float16* WLp1 = (_Float16*)(ws + oWLp1);
  _Float16* WHp2 = (_Float16*)(ws + oWHp2); _Float16* WLp2 = (_Float16*)(ws + oWLp2);
  _Float16* WHm1 = (_Float16*)(ws + oWHm1); _Float16* WLm1 = (_Float16*)(ws + oWLm1);
  _Float16* WHm2 = (_Float16*)(ws + oWHm2); _Float16* WLm2 = (_Float16*)(ws + oWLm2);
  _Float16* WHm3 = (_Float16*)(ws + oWHm3); _Float16* WLm3 = (_Float16*)(ws + oWLm3);
  // MoE weights alias the m-layer split weights (converted AFTER the trunk,
  // re-split at the top of each outer iteration):
  __bf16* WBex = (__bf16*)(ws + oWHm1);   // 16 MB over WHm1+WLm1
  __bf16* WBfu = (__bf16*)(ws + oWHm2);   //  4 MB over WHm2
  _Float16* PH0 = (_Float16*)(ws + oP);
  _Float16* PL0 = (_Float16*)(ws + oP + (size_t)CT * 4096);
  _Float16* PH1 = (_Float16*)(ws + oP + 2 * (size_t)CT * 4096);
  _Float16* PL1 = (_Float16*)(ws + oP + 3 * (size_t)CT * 4096);
  float* F32    = (float*)(ws + oP);      // CT x 2048 f32 (planes 0-1)
  __bf16* ACCb  = (__bf16*)(ws + oP);     // CM x 1024 bf16 (rank-0 partial)
  float* F32fus = (float*)(ws + oP);      // CM x 1024 f32 (fus output)
  __bf16* BFA = (__bf16*)(ws + oBFA);     // LN output bf16, CM x 2048
  __bf16* BFB = (__bf16*)(ws + oBFB);     // moe concat bf16, CM x 2048
  int*   sel  = (int*)(ws + oSel);
  float* selw = (float*)(ws + oSelw);
  int*   lrow = (int*)(ws + oLrow);
  float* lw   = (float*)(ws + oLw);
  int*   blkexp = (int*)(ws + oBlk);
  int*   cnt = (int*)(ws + oCnt);
  int*   cur = (int*)(ws + oCur);
  float* s1v = (float*)(ws + oS1); float* t1v = (float*)(ws + oT1);
  float* s2v = (float*)(ws + oS2); float* t2v = (float*)(ws + oT2);
  float* fsv = (float*)(ws + oFS); float* ftv = (float*)(ws + oFT);

  const dim3 T(256);
  // ---- once: fold BN vectors, p-layer splits (never clobbered) ----
  fold_kernel<<<8, T, 0, stream>>>(bn1_g, bn1_b, m1_b, bn2_g, bn2_b, m2_b,
                                   bnf_g, bnf_b, fus_b, s1v, t1v, s2v, t2v, fsv, ftv);
  split_w<<<1024, T, 0, stream>>>(p1_w, WHp1, WLp1, 1048576);
  split_w<<<1024, T, 0, stream>>>(p2_w, WHp2, WLp2, 1048576);

  const dim3 GP(CT / 128, 8, 2), GT16(CT / 128, 16, 1), GM(NBLK, 8), GF(CM / 128, 8);
  for (int m0 = 0; m0 < BROWS; m0 += CM) {
    // m-layer split weights (region shared with WBex/WBfu -> re-split)
    split_w<<<4096, T, 0, stream>>>(m1_w, WHm1, WLm1, 4194304);
    split_w<<<4096, T, 0, stream>>>(m2_w, WHm2, WLm2, 4194304);
    split_w<<<4096, T, 0, stream>>>(m3_w, WHm3, WLm3, 4194304);

    // ---- trunk, inner-chunked at CT ----
    for (int r0 = 0; r0 < CM; r0 += CT) {
      const float* x1c = x1 + (size_t)(m0 + r0) * 1024;
      const float* x2c = x2 + (size_t)(m0 + r0) * 1024;
      prep_x<<<CT, T, 0, stream>>>(x1c, x2c, PH0, PL0);
      // p1 + p2 merged (z selects weight set; A/C offset by 1024 cols)
      gemm_split<0><<<GP, T, 0, stream>>>(PH0, PL0, WHp1, WLp1, WHp2, WLp2,
                                          2048, 1024, 1024,
                                          PH1, PL1, nullptr, 2048,
                                          p1_b, nullptr, p2_b, 1024);
      gemm_split<1><<<GT16, T, 0, stream>>>(PH1, PL1, WHm1, WLm1, WHm1, WLm1,
                                            2048, 2048, 2048,
                                            PH0, PL0, nullptr, 2048,
                                            s1v, t1v, s1v, 0);
      gemm_split<1><<<GT16, T, 0, stream>>>(PH0, PL0, WHm2, WLm2, WHm2, WLm2,
                                            2048, 2048, 2048,
                                            PH1, PL1, nullptr, 2048,
                                            s2v, t2v, s2v, 0);
      gemm_split<2><<<GT16, T, 0, stream>>>(PH1, PL1, WHm3, WLm3, WHm3, WLm3,
                                            2048, 2048, 2048,
                                            nullptr, nullptr, F32, 2048,
                                            m3_b, nullptr, m3_b, 0);
      // LN + fused gate (writes BFA bf16 + sel/selw; no F32 writeback)
      ln_gate_kernel<<<CT, T, 0, stream>>>(F32, BFA + (size_t)r0 * 2048,
                                           ln_g, ln_b, gate_w, gate_b,
                                           sel, selw, r0, CM * 2);
    }

    // ---- MoE weights (clobber m-layer splits now that trunk is done) ----
    cvt_bf<<<8192, T, 0, stream>>>(ex_w, WBex, 8388608);
    cvt_bf<<<2048, T, 0, stream>>>(fus_w, WBfu, 2097152);

    // ---- full-batch MoE (ballot-aggregated bucketing) ----
    hipMemsetAsync(cnt, 0, 32 * 4, stream);
    count_kernel<<<(2 * CM + 255) / 256, T, 0, stream>>>(sel, cnt, CM);
    prefix_kernel<<<1, T, 0, stream>>>(cnt, cur, blkexp, NBLK);
    hipMemsetAsync(lrow, 0xFF, (size_t)4 * LCAP * 4, stream);
    scatter_kernel<<<(2 * CM + 255) / 256, T, 0, stream>>>(sel, selw, cur, lrow, lw, CM, LCAP);
    for (int h = 0; h < 2; ++h) {
      const int g0 = h * 2, g1 = h * 2 + 1;
      gemm_moe<0><<<GM, T, 0, stream>>>(BFA + h * 1024, WBex,
                                        lrow + (size_t)g0 * LCAP, lw + (size_t)g0 * LCAP,
                                        blkexp + g0 * NBLK, ex_b, ACCb, nullptr);
      gemm_moe<1><<<GM, T, 0, stream>>>(BFA + h * 1024, WBex,
                                        lrow + (size_t)g1 * LCAP, lw + (size_t)g1 * LCAP,
                                        blkexp + g1 * NBLK, ex_b, ACCb, BFB + h * 1024);
    }

    // ---- fus + reg on the full outer chunk ----
    gemm_fus<<<GF, T, 0, stream>>>(BFB, WBfu, 2048, 2048, 2048, F32fus, 1024, fsv, ftv);
    reg_kernel<<<CM / 4, T, 0, stream>>>(F32fus, reg_w, reg_b, (float*)d_out + m0);
  }
}

// Round 11
// 1758.975 us; speedup vs baseline: 1.1712x; 1.0249x over previous
//
#include <hip/hip_runtime.h>
#include <stdint.h>
#include <math.h>

#define BROWS 16384

typedef _Float16 h8 __attribute__((ext_vector_type(8)));
typedef _Float16 h4 __attribute__((ext_vector_type(4)));
typedef __bf16   b8 __attribute__((ext_vector_type(8)));
typedef __bf16   b4 __attribute__((ext_vector_type(4)));
typedef float    f4 __attribute__((ext_vector_type(4)));

typedef __attribute__((address_space(3))) char       lds_char;
typedef __attribute__((address_space(1))) const char gbl_char;

// async global->LDS, 16B per lane; LDS dest = wave-uniform base + lane*16
// (global SOURCE address is per-lane -> usable as gather AND as pre-swizzle)
__device__ __forceinline__ void gload16(const void* g, void* l) {
  __builtin_amdgcn_global_load_lds((const gbl_char*)(uintptr_t)g,
                                   (lds_char*)(uintptr_t)l, 16, 0, 0);
}

// BK=64 tile: [128 rows][64 halfs] = 16KB/plane, row stride 128B.
// LDS(row, cb) holds global colblock cb^(row&7)  [staged via pre-swizzled
// per-lane global source colbyte ((l&7)^(l>>3))*16, linear LDS dest].
// 16x16x32 fragment read at colblock ((ks*4 + (lane>>4)) ^ (lane&7)):
// measured conflict-free (round 7: SQ_LDS_BANK_CONFLICT == 0).

// ---------------------------------------------------------------------------
// fp16 2-term split GEMM:  C = A @ W^T (+epilogue), A = Ah + Al/2048,
// W = Wh + Wl/2048, row-major, K contiguous. blockIdx.z selects second
// weight set / bias and offsets A,C by zoff (merged p1+p2 launch).
// EPI 0: y += v0[col]; write split planes Ch/Cl          (p1, p2)
// EPI 1: y = relu(y*v0[col] + v1[col]); write Ch/Cl      (m1, m2)
// EPI 2: Cf = y + v0[col]  (f32)                          (m3)
// ---------------------------------------------------------------------------
template<int EPI>
__global__ __launch_bounds__(256, 2)
void gemm_split(const _Float16* __restrict__ Ah, const _Float16* __restrict__ Al,
                const _Float16* __restrict__ Wh, const _Float16* __restrict__ Wl,
                const _Float16* __restrict__ WhB, const _Float16* __restrict__ WlB,
                const int lda, const int ldw, const int K,
                _Float16* __restrict__ Ch, _Float16* __restrict__ Cl,
                float* __restrict__ Cf, const int ldc,
                const float* __restrict__ v0, const float* __restrict__ v1,
                const float* __restrict__ v0B, const int zoff)
{
  __shared__ char smem[65536];
  char* const sAh = smem;
  char* const sAl = smem + 16384;
  char* const sWh = smem + 32768;
  char* const sWl = smem + 49152;

  if (blockIdx.z) {               // wave-uniform select (p2 of the merged pair)
    Wh = WhB; Wl = WlB; v0 = v0B;
    Ah += zoff; Al += zoff; Ch += zoff; Cl += zoff;
  }

  const int tid  = threadIdx.x;
  const int wid  = tid >> 6, lane = tid & 63;
  const int bm = blockIdx.x, bn = blockIdx.y;
  const int wr = wid >> 1, wc = wid & 1;          // 2x2 waves, 64x64 each
  const int sr  = lane >> 3;                      // staging row-in-8
  const int scb = ((lane & 7) ^ sr) * 16;         // pre-swizzled source colbyte
  const int fr  = lane & 15;                      // fragment row
  const int sw0 = ((lane >> 4) ^ (lane & 7)) * 16;        // read swz, ks=0
  const int sw1 = ((4 + (lane >> 4)) ^ (lane & 7)) * 16;  // read swz, ks=1

  f4 accA[4][4] = {};
  f4 accB[4][4] = {};

  const size_t arow0 = (size_t)bm * 128;
  const size_t wrow0 = (size_t)bn * 128;

  for (int k0 = 0; k0 < K; k0 += 64) {
    __syncthreads();
#pragma unroll
    for (int i = 0; i < 4; ++i) {
      const int rb = wid * 32 + i * 8;
      const size_t ga = (arow0 + rb + sr) * (size_t)lda + k0;
      const size_t gw = (wrow0 + rb + sr) * (size_t)ldw + k0;
      const int lo = rb * 128;                    // wave-uniform LDS base
      gload16((const char*)(Ah + ga) + scb, sAh + lo);
      gload16((const char*)(Al + ga) + scb, sAl + lo);
      gload16((const char*)(Wh + gw) + scb, sWh + lo);
      gload16((const char*)(Wl + gw) + scb, sWl + lo);
    }
    __syncthreads();

#pragma unroll
    for (int ks = 0; ks < 2; ++ks) {
      const int sw = ks ? sw1 : sw0;
      h8 ah[4], al[4], bh[4], bl[4];
#pragma unroll
      for (int mi = 0; mi < 4; ++mi) {
        const int r = (wr * 64 + mi * 16 + fr) * 128 + sw;
        ah[mi] = *(const h8*)(sAh + r);
        al[mi] = *(const h8*)(sAl + r);
      }
#pragma unroll
      for (int ni = 0; ni < 4; ++ni) {
        const int r = (wc * 64 + ni * 16 + fr) * 128 + sw;
        bh[ni] = *(const h8*)(sWh + r);
        bl[ni] = *(const h8*)(sWl + r);
      }
#pragma unroll
      for (int mi = 0; mi < 4; ++mi)
#pragma unroll
        for (int ni = 0; ni < 4; ++ni) {
          accA[mi][ni] = __builtin_amdgcn_mfma_f32_16x16x32_f16(ah[mi], bh[ni], accA[mi][ni], 0, 0, 0);
          accB[mi][ni] = __builtin_amdgcn_mfma_f32_16x16x32_f16(ah[mi], bl[ni], accB[mi][ni], 0, 0, 0);
          accB[mi][ni] = __builtin_amdgcn_mfma_f32_16x16x32_f16(al[mi], bh[ni], accB[mi][ni], 0, 0, 0);
        }
    }
  }

  const int rg = (lane >> 4) * 4;                 // C/D: col=lane&15, row=(lane>>4)*4+j
#pragma unroll
  for (int mi = 0; mi < 4; ++mi)
#pragma unroll
    for (int ni = 0; ni < 4; ++ni) {
      const int gcol = bn * 128 + wc * 64 + ni * 16 + fr;
      const float a0 = v0[gcol];
      const float a1 = (EPI == 1) ? v1[gcol] : 0.f;
#pragma unroll
      for (int j = 0; j < 4; ++j) {
        const size_t grow = arow0 + wr * 64 + mi * 16 + rg + j;
        float y = accA[mi][ni][j] + accB[mi][ni][j] * (1.f / 2048.f);
        const size_t off = grow * (size_t)ldc + gcol;
        if constexpr (EPI == 0) {
          y += a0;
          const _Float16 hh = (_Float16)y;
          Ch[off] = hh;
          Cl[off] = (_Float16)((y - (float)hh) * 2048.f);
        } else if constexpr (EPI == 1) {
          y = fmaxf(fmaf(y, a0, a1), 0.f);
          const _Float16 hh = (_Float16)y;
          Ch[off] = hh;
          Cl[off] = (_Float16)((y - (float)hh) * 2048.f);
        } else {
          Cf[off] = y + a0;
        }
      }
    }
}

// ---------------------------------------------------------------------------
// bf16 GEMM for the fus layer: Cf = (A @ W^T)*v0[col] + v1[col]   (BK=64)
// ---------------------------------------------------------------------------
__global__ __launch_bounds__(256, 2)
void gemm_fus(const __bf16* __restrict__ A, const __bf16* __restrict__ W,
              const int lda, const int ldw, const int K,
              float* __restrict__ Cf, const int ldc,
              const float* __restrict__ v0, const float* __restrict__ v1)
{
  __shared__ char smem[32768];
  char* const sA = smem;
  char* const sW = smem + 16384;

  const int tid  = threadIdx.x;
  const int wid  = tid >> 6, lane = tid & 63;
  const int bm = blockIdx.x, bn = blockIdx.y;
  const int wr = wid >> 1, wc = wid & 1;
  const int sr  = lane >> 3;
  const int scb = ((lane & 7) ^ sr) * 16;
  const int fr  = lane & 15;
  const int sw0 = ((lane >> 4) ^ (lane & 7)) * 16;
  const int sw1 = ((4 + (lane >> 4)) ^ (lane & 7)) * 16;

  f4 acc[4][4] = {};

  const size_t arow0 = (size_t)bm * 128;
  const size_t wrow0 = (size_t)bn * 128;

  for (int k0 = 0; k0 < K; k0 += 64) {
    __syncthreads();
#pragma unroll
    for (int i = 0; i < 4; ++i) {
      const int rb = wid * 32 + i * 8;
      const size_t ga = (arow0 + rb + sr) * (size_t)lda + k0;
      const size_t gw = (wrow0 + rb + sr) * (size_t)ldw + k0;
      const int lo = rb * 128;
      gload16((const char*)(A + ga) + scb, sA + lo);
      gload16((const char*)(W + gw) + scb, sW + lo);
    }
    __syncthreads();

#pragma unroll
    for (int ks = 0; ks < 2; ++ks) {
      const int sw = ks ? sw1 : sw0;
      b8 av[4], bv[4];
#pragma unroll
      for (int mi = 0; mi < 4; ++mi)
        av[mi] = *(const b8*)(sA + (wr * 64 + mi * 16 + fr) * 128 + sw);
#pragma unroll
      for (int ni = 0; ni < 4; ++ni)
        bv[ni] = *(const b8*)(sW + (wc * 64 + ni * 16 + fr) * 128 + sw);
#pragma unroll
      for (int mi = 0; mi < 4; ++mi)
#pragma unroll
        for (int ni = 0; ni < 4; ++ni)
          acc[mi][ni] = __builtin_amdgcn_mfma_f32_16x16x32_bf16(av[mi], bv[ni], acc[mi][ni], 0, 0, 0);
    }
  }

  const int rg = (lane >> 4) * 4;
#pragma unroll
  for (int mi = 0; mi < 4; ++mi)
#pragma unroll
    for (int j = 0; j < 4; ++j) {
      const size_t grow = arow0 + wr * 64 + mi * 16 + rg + j;
#pragma unroll
      for (int ni = 0; ni < 4; ++ni) {
        const int gcol = bn * 128 + wc * 64 + ni * 16 + fr;
        Cf[grow * (size_t)ldc + gcol] = fmaf(acc[mi][ni][j], v0[gcol], v1[gcol]);
      }
    }
}

// ---------------------------------------------------------------------------
// gathered per-(half,rank) expert GEMM (BK=64). z = half (both halves of a
// rank-pass in one dispatch; independent). Block bx: 128 worklist rows, all
// expert blkexp[bx]; by = 128-col tile. A rows gathered via per-lane
// global_load_lds source addresses (pre-swizzled cols). bx XCD-chunk
// swizzled (bijective, NBLK % 8 == 0).
// PASS 0: ACCb[(h*CM+R)][col] = bf16( w * ((A[row]@We^T)[col] + be[col]) )
// PASS 1: BFBh[row][col]      = bf16( ACCb[(h*CM+R)][col] + w * (...) )
// Row-unique writers per pass -> bit-deterministic regardless of scatter order.
// ---------------------------------------------------------------------------
template<int PASS>
__global__ __launch_bounds__(256, 2)
void gemm_moe(const __bf16* __restrict__ A0,     // BFA (lda 2048)
              const __bf16* __restrict__ Wall,   // 8 x (1024x1024) bf16
              const int* __restrict__ lrow, const float* __restrict__ lw,
              const int* __restrict__ blkexp,
              const float* __restrict__ eb,      // ex_b (8x1024)
              __bf16* __restrict__ ACCb,         // 2*CM x 1024 bf16
              __bf16* __restrict__ BFB,          // CM x 2048 bf16
              const int CM, const int LCAP, const int NBLK, const int rank)
{
  const int nb = gridDim.x;                       // NBLK, divisible by 8
  const int bx = (blockIdx.x & 7) * (nb >> 3) + (blockIdx.x >> 3);
  const int by = blockIdx.y;
  const int h  = blockIdx.z;
  const int g  = h * 2 + rank;
  const int e = blkexp[g * NBLK + bx];
  if (e < 0) return;                              // fully-pad block

  __shared__ char smem[32768];
  __shared__ int   slrow[128];
  __shared__ float slw[128];
  char* const sA = smem;
  char* const sW = smem + 16384;

  const int tid  = threadIdx.x;
  const int wid  = tid >> 6, lane = tid & 63;
  if (tid < 128) {
    slrow[tid] = lrow[(size_t)g * LCAP + bx * 128 + tid];
    slw[tid]   = lw[(size_t)g * LCAP + bx * 128 + tid];
  }
  __syncthreads();

  const __bf16* A = A0 + h * 1024;
  const __bf16* W = Wall + (size_t)e * 1048576 + (size_t)by * 131072;

  const int wr = wid >> 1, wc = wid & 1;
  const int sr  = lane >> 3;
  const int scb = ((lane & 7) ^ sr) * 16;
  const int fr  = lane & 15;
  const int sw0 = ((lane >> 4) ^ (lane & 7)) * 16;
  const int sw1 = ((4 + (lane >> 4)) ^ (lane & 7)) * 16;

  // per-lane gathered A base pointers (4 staging loads per wave)
  const char* abase[4];
#pragma unroll
  for (int i = 0; i < 4; ++i) {
    int s = slrow[wid * 32 + i * 8 + sr];
    if (s < 0) s = 0;
    abase[i] = (const char*)(A + (size_t)s * 2048) + scb;
  }

  f4 acc[4][4] = {};

  for (int k0 = 0; k0 < 1024; k0 += 64) {
    __syncthreads();
#pragma unroll
    for (int i = 0; i < 4; ++i) {
      const int rb = wid * 32 + i * 8;
      const int lo = rb * 128;
      gload16(abase[i] + (size_t)k0 * 2, sA + lo);
      gload16((const char*)(W + (size_t)(rb + sr) * 1024 + k0) + scb, sW + lo);
    }
    __syncthreads();

#pragma unroll
    for (int ks = 0; ks < 2; ++ks) {
      const int sw = ks ? sw1 : sw0;
      b8 av[4], bv[4];
#pragma unroll
      for (int mi = 0; mi < 4; ++mi)
        av[mi] = *(const b8*)(sA + (wr * 64 + mi * 16 + fr) * 128 + sw);
#pragma unroll
      for (int ni = 0; ni < 4; ++ni)
        bv[ni] = *(const b8*)(sW + (wc * 64 + ni * 16 + fr) * 128 + sw);
#pragma unroll
      for (int mi = 0; mi < 4; ++mi)
#pragma unroll
        for (int ni = 0; ni < 4; ++ni)
          acc[mi][ni] = __builtin_amdgcn_mfma_f32_16x16x32_bf16(av[mi], bv[ni], acc[mi][ni], 0, 0, 0);
    }
  }

  const int rg = (lane >> 4) * 4;
  const float* ebp = eb + (size_t)e * 1024;
#pragma unroll
  for (int mi = 0; mi < 4; ++mi)
#pragma unroll
    for (int j = 0; j < 4; ++j) {
      const int local = wr * 64 + mi * 16 + rg + j;
      const int R = slrow[local];
      if (R < 0) continue;
      const float w = slw[local];
#pragma unroll
      for (int ni = 0; ni < 4; ++ni) {
        const int gcol = by * 128 + wc * 64 + ni * 16 + fr;
        const float v = w * (acc[mi][ni][j] + ebp[gcol]);
        const size_t aoff = ((size_t)h * CM + R) * 1024 + gcol;
        if constexpr (PASS == 0) {
          ACCb[aoff] = (__bf16)v;
        } else {
          BFB[(size_t)R * 2048 + h * 1024 + gcol] = (__bf16)((float)ACCb[aoff] + v);
        }
      }
    }
}

// --------------------------- prep / elementwise ----------------------------

__global__ void split_w(const float* __restrict__ src, _Float16* __restrict__ dh,
                        _Float16* __restrict__ dl, const size_t n)
{
  const size_t i = ((size_t)blockIdx.x * 256 + threadIdx.x) * 4;
  if (i >= n) return;
  const f4 v = *(const f4*)(src + i);
  h4 hh, ll;
#pragma unroll
  for (int j = 0; j < 4; ++j) {
    const _Float16 h = (_Float16)v[j];
    hh[j] = h;
    ll[j] = (_Float16)((v[j] - (float)h) * 2048.f);
  }
  *(h4*)(dh + i) = hh;
  *(h4*)(dl + i) = ll;
}

__global__ void cvt_bf(const float* __restrict__ src, __bf16* __restrict__ dst, const size_t n)
{
  const size_t i = ((size_t)blockIdx.x * 256 + threadIdx.x) * 4;
  if (i >= n) return;
  const f4 v = *(const f4*)(src + i);
  b4 o;
#pragma unroll
  for (int j = 0; j < 4; ++j) o[j] = (__bf16)v[j];
  *(b4*)(dst + i) = o;
}

// x1 -> cols [0,1024), x2 -> cols [1024,2048) of split planes (lda 2048).
// 8 floats / thread (c block of 8 never straddles the 1024 boundary).
__global__ void prep_x(const float* __restrict__ x1, const float* __restrict__ x2,
                       _Float16* __restrict__ ph, _Float16* __restrict__ pl)
{
  const size_t i = ((size_t)blockIdx.x * 256 + threadIdx.x) * 8;
  const int b = (int)(i >> 11);
  const int c = (int)(i & 2047);
  const float* s = (c < 1024) ? (x1 + (size_t)b * 1024 + c)
                              : (x2 + (size_t)b * 1024 + (c - 1024));
  const f4 v0 = *(const f4*)s;
  const f4 v1 = *(const f4*)(s + 4);
  h8 hh, ll;
#pragma unroll
  for (int j = 0; j < 4; ++j) {
    const _Float16 h0 = (_Float16)v0[j];
    hh[j] = h0;
    ll[j] = (_Float16)((v0[j] - (float)h0) * 2048.f);
    const _Float16 h1 = (_Float16)v1[j];
    hh[4 + j] = h1;
    ll[4 + j] = (_Float16)((v1[j] - (float)h1) * 2048.f);
  }
  *(h8*)(ph + i) = hh;
  *(h8*)(pl + i) = ll;
}

// fold BN-eval into per-col scale/shift: s = g/sqrt(1+eps), t = mb*s + b
__global__ void fold_kernel(const float* g1, const float* b1, const float* mb1,
                            const float* g2, const float* b2, const float* mb2,
                            const float* gf, const float* bf, const float* fb,
                            float* s1, float* t1, float* s2, float* t2,
                            float* fs, float* ft)
{
  const int t = blockIdx.x * 256 + threadIdx.x;
  const float inv = (float)(1.0 / sqrt(1.0 + 1.0e-5));
  if (t < 2048) {
    float a = g1[t] * inv; s1[t] = a; t1[t] = mb1[t] * a + b1[t];
    float c = g2[t] * inv; s2[t] = c; t2[t] = mb2[t] * c + b2[t];
  }
  if (t < 1024) {
    float a = gf[t] * inv; fs[t] = a; ft[t] = fb[t] * a + bf[t];
  }
}

// LayerNorm over 2048 cols -> bf16 out; FUSED gate (top2 softmax -> sel/selw).
// f32 stats + f32 gate dots: stat error -> logit error ~6e-8, 100x under the
// min top-2 logit gap (~6e-6). Validated f32-dot path rounds 8-10.
__global__ __launch_bounds__(256)
void ln_gate_kernel(const float* __restrict__ xf, __bf16* __restrict__ xb,
                    const float* __restrict__ lg, const float* __restrict__ lb,
                    const float* __restrict__ gw, const float* __restrict__ gb,
                    int* __restrict__ sel, float* __restrict__ selw,
                    const int rowbase, const int CM2)
{
  const int row = blockIdx.x;
  const float* xr = xf + (size_t)row * 2048;
  const int tid = threadIdx.x;
  const int wid = tid >> 6, lane = tid & 63;
  const f4 v0 = *(const f4*)(xr + tid * 4);
  const f4 v1 = *(const f4*)(xr + 1024 + tid * 4);
  float s = 0.f, ss = 0.f;
#pragma unroll
  for (int j = 0; j < 4; ++j) {
    s  += v0[j] + v1[j];
    ss += v0[j] * v0[j] + v1[j] * v1[j];
  }
#pragma unroll
  for (int o = 32; o; o >>= 1) { s += __shfl_xor(s, o); ss += __shfl_xor(ss, o); }
  __shared__ float red[8];
  if (!lane) { red[wid] = s; red[4 + wid] = ss; }
  __syncthreads();
  const float S  = red[0] + red[1] + red[2] + red[3];
  const float SS = red[4] + red[5] + red[6] + red[7];
  const float mu = S * (1.f / 2048.f);
  const float var = SS * (1.f / 2048.f) - mu * mu;
  const float inv = (float)(1.0 / sqrt((double)var + 1.0e-5));
  const float muf = mu;
  f4 o0, o1;
  b4 q0, q1;
#pragma unroll
  for (int j = 0; j < 4; ++j) {
    const int c0 = tid * 4 + j, c1 = 1024 + tid * 4 + j;
    o0[j] = (v0[j] - muf) * inv * lg[c0] + lb[c0];
    o1[j] = (v1[j] - muf) * inv * lg[c1] + lb[c1];
    q0[j] = (__bf16)o0[j];
    q1[j] = (__bf16)o1[j];
  }
  *(b4*)(xb + (size_t)row * 2048 + tid * 4) = q0;
  *(b4*)(xb + (size_t)row * 2048 + 1024 + tid * 4) = q1;

  // ---- fused gate: 16 dots (2 halves x 8 experts), f32 FMA + f32 reduce ----
  float l0[8], l1[8];
#pragma unroll
  for (int e = 0; e < 8; ++e) {
    const f4 w = *(const f4*)(gw + e * 1024 + tid * 4);
    l0[e] = o0[0] * w[0] + o0[1] * w[1] + o0[2] * w[2] + o0[3] * w[3];
    l1[e] = o1[0] * w[0] + o1[1] * w[1] + o1[2] * w[2] + o1[3] * w[3];
  }
#pragma unroll
  for (int o = 32; o; o >>= 1)
#pragma unroll
    for (int e = 0; e < 8; ++e) {
      l0[e] += __shfl_xor(l0[e], o);
      l1[e] += __shfl_xor(l1[e], o);
    }
  __shared__ float red2[4][16];
  if (!lane)
#pragma unroll
    for (int e = 0; e < 8; ++e) { red2[wid][e] = l0[e]; red2[wid][8 + e] = l1[e]; }
  __syncthreads();
  if (tid < 2) {                     // tid 0: half 0, tid 1: half 1
    const int h = tid;
    float lg8[8];
#pragma unroll
    for (int e = 0; e < 8; ++e)
      lg8[e] = red2[0][h * 8 + e] + red2[1][h * 8 + e] + red2[2][h * 8 + e]
             + red2[3][h * 8 + e] + gb[e];
    int i0 = 0;
    for (int e = 1; e < 8; ++e) if (lg8[e] > lg8[i0]) i0 = e;
    int i1 = -1;
    for (int e = 0; e < 8; ++e) if (e != i0 && (i1 < 0 || lg8[e] > lg8[i1])) i1 = e;
    const double p = exp((double)lg8[i1] - (double)lg8[i0]);
    const double z = 1.0 + p;
    int* sp = sel + h * CM2 + (size_t)(rowbase + row) * 2;
    float* wp = selw + h * CM2 + (size_t)(rowbase + row) * 2;
    sp[0] = i0; wp[0] = (float)(1.0 / z);
    sp[1] = i1; wp[1] = (float)(p / z);
  }
}

// wave-aggregated per-(half,rank) expert histogram: <=16 atomics per wave
__global__ void count_kernel(const int* __restrict__ sel, int* __restrict__ cnt,
                             const int CM)
{
  const int idx = blockIdx.x * 256 + threadIdx.x;   // h*CM + row
  const bool valid = idx < 2 * CM;
  const int h = (idx / CM) & 1;                     // wave-uniform (CM % 64 == 0)
  const int lane = threadIdx.x & 63;
#pragma unroll
  for (int r = 0; r < 2; ++r) {
    const int e = valid ? sel[idx * 2 + r] : -1;
    const int g = h * 2 + r;
    for (int ee = 0; ee < 8; ++ee) {
      const unsigned long long mask = __ballot(e == ee);
      if (mask && lane == __ffsll((unsigned long long)mask) - 1)
        atomicAdd(&cnt[g * 8 + ee], __popcll(mask));
    }
  }
}

// 128-aligned segment starts + block->expert maps for 4 groups (h,r)
__global__ void prefix_kernel(const int* __restrict__ cnt, int* __restrict__ cursor,
                              int* __restrict__ blkexp, const int NBLK)
{
  const int tid = threadIdx.x;
  for (int i = tid; i < 4 * NBLK; i += 256) blkexp[i] = -1;
  __syncthreads();
  if (tid < 32) {
    const int g = tid >> 3, e = tid & 7;      // g = h*2 + r
    int off = 0;
    for (int j = 0; j < e; ++j) off += ((cnt[g * 8 + j] + 127) >> 7) << 7;
    cursor[g * 8 + e] = off;
    const int nb = (cnt[g * 8 + e] + 127) >> 7;
    for (int b = 0; b < nb; ++b) blkexp[g * NBLK + (off >> 7) + b] = e;
  }
}

// fill per-(half,rank) work-lists via ballot aggregation: one atomic per
// (wave, expert) with popcount; lanes derive slots from mask prefix-pop.
__global__ void scatter_kernel(const int* __restrict__ sel, const float* __restrict__ selw,
                               int* __restrict__ cursor,
                               int* __restrict__ lrow, float* __restrict__ lw,
                               const int CM, const int LCAP)
{
  const int idx = blockIdx.x * 256 + threadIdx.x;   // h*CM + row
  const bool valid = idx < 2 * CM;
  const int h = (idx / CM) & 1;                     // wave-uniform (CM % 64 == 0)
  const int R = valid ? (idx - (idx / CM) * CM) : 0;
  const int lane = threadIdx.x & 63;
#pragma unroll
  for (int r = 0; r < 2; ++r) {
    const int e = valid ? sel[idx * 2 + r] : -1;
    const int g = h * 2 + r;
    int pos = -1;
    for (int ee = 0; ee < 8; ++ee) {
      const unsigned long long mask = __ballot(e == ee);
      if (mask) {
        const int leader = __ffsll((unsigned long long)mask) - 1;
        int base = 0;
        if (lane == leader) base = atomicAdd(&cursor[g * 8 + ee], __popcll(mask));
        base = __shfl(base, leader);
        if (e == ee)
          pos = base + __popcll(mask & ((1ull << lane) - 1ull));
      }
    }
    if (valid) {
      lrow[(size_t)g * LCAP + pos] = R;
      lw[(size_t)g * LCAP + pos] = selw[idx * 2 + r];
    }
  }
}

// out[row] = dot(fused_row, reg_w) + reg_b
__global__ __launch_bounds__(256)
void reg_kernel(const float* __restrict__ xf, const float* __restrict__ rw,
                const float* __restrict__ rb, float* __restrict__ out)
{
  const int wid = threadIdx.x >> 6, lane = threadIdx.x & 63;
  const int row = blockIdx.x * 4 + wid;
  const float* xr = xf + (size_t)row * 1024;
  double acc = 0.0;
#pragma unroll
  for (int i = 0; i < 4; ++i) {
    const int f = (lane + 64 * i) * 4;
    const f4 a = *(const f4*)(xr + f);
    const f4 w = *(const f4*)(rw + f);
    acc += (double)a[0] * w[0] + (double)a[1] * w[1] + (double)a[2] * w[2] + (double)a[3] * w[3];
  }
#pragma unroll
  for (int o = 32; o; o >>= 1) acc += __shfl_xor(acc, o);
  if (!lane) out[row] = (float)(acc + (double)rb[0]);
}

// ---------------------------------------------------------------------------

extern "C" void kernel_launch(void* const* d_in, const int* in_sizes, int n_in,
                              void* d_out, int out_size, void* d_ws, size_t ws_size,
                              hipStream_t stream)
{
  (void)in_sizes; (void)n_in; (void)out_size;
  const float* x1    = (const float*)d_in[0];
  const float* x2    = (const float*)d_in[1];
  const float* p1_w  = (const float*)d_in[2];
  const float* p1_b  = (const float*)d_in[3];
  const float* p2_w  = (const float*)d_in[4];
  const float* p2_b  = (const float*)d_in[5];
  const float* m1_w  = (const float*)d_in[6];
  const float* m1_b  = (const float*)d_in[7];
  const float* bn1_g = (const float*)d_in[8];
  const float* bn1_b = (const float*)d_in[9];
  const float* m2_w  = (const float*)d_in[10];
  const float* m2_b  = (const float*)d_in[11];
  const float* bn2_g = (const float*)d_in[12];
  const float* bn2_b = (const float*)d_in[13];
  const float* m3_w  = (const float*)d_in[14];
  const float* m3_b  = (const float*)d_in[15];
  const float* ln_g  = (const float*)d_in[16];
  const float* ln_b  = (const float*)d_in[17];
  const float* ex_w  = (const float*)d_in[18];
  const float* ex_b  = (const float*)d_in[19];
  const float* gate_w= (const float*)d_in[20];
  const float* gate_b= (const float*)d_in[21];
  const float* fus_w = (const float*)d_in[22];
  const float* fus_b = (const float*)d_in[23];
  const float* bnf_g = (const float*)d_in[24];
  const float* bnf_b = (const float*)d_in[25];
  const float* reg_w = (const float*)d_in[26];
  const float* reg_b = (const float*)d_in[27];

  char* ws = (char*)d_ws;
  size_t off = 0;
  auto alloc = [&](size_t bytes) { size_t o = off; off += (bytes + 255) & ~(size_t)255; return o; };

  // ---- fixed region: trunk split weights + folded vectors (~56 MB) ----
  const size_t oWHp1 = alloc((size_t)1048576 * 2), oWLp1 = alloc((size_t)1048576 * 2);
  const size_t oWHp2 = alloc((size_t)1048576 * 2), oWLp2 = alloc((size_t)1048576 * 2);
  const size_t oWHm1 = alloc((size_t)4194304 * 2), oWLm1 = alloc((size_t)4194304 * 2);
  const size_t oWHm2 = alloc((size_t)4194304 * 2), oWLm2 = alloc((size_t)4194304 * 2);
  const size_t oWHm3 = alloc((size_t)4194304 * 2), oWLm3 = alloc((size_t)4194304 * 2);
  const size_t oS1 = alloc(2048 * 4), oT1 = alloc(2048 * 4);
  const size_t oS2 = alloc(2048 * 4), oT2 = alloc(2048 * 4);
  const size_t oFS = alloc(1024 * 4), oFT = alloc(1024 * 4);
  const size_t oCnt = alloc(32 * 4), oCur = alloc(32 * 4);
  const size_t fixedEnd = off;

  // ---- choose outer chunk CM (MoE batch) so everything fits ws_size ----
  int CM = BROWS;
  while (CM > 2048) {
    const int ct = (CM < 4096) ? CM : 4096;
    const size_t nblk = (size_t)CM / 128 + 8;
    const size_t lcap = nblk * 128;
    const size_t need = fixedEnd
                      + 4 * ((size_t)ct * 4096 + 256)   // P planes (>= 2*CM*1024 bf16 ACCb)
                      + 2 * ((size_t)CM * 4096 + 256)   // BFA + BFB
                      + 2 * ((size_t)CM * 16 + 256)     // sel + selw
                      + 2 * (4 * lcap * 4 + 256)        // lrow + lw (4 groups)
                      + (4 * nblk * 4 + 256) + 8192;    // blkexp
    if (ws_size >= need) break;
    CM >>= 1;
  }
  const int CT = (CM < 4096) ? CM : 4096;
  const int NBLK = CM / 128 + 8;                   // divisible by 8 for CM>=1024
  const int LCAP = NBLK * 128;

  // P region: 4 fp16 planes (CT x 2048) == 2*CM*1024 bf16 ACCb == CM*1024 f32
  // (all phases disjoint in time).
  const size_t pBytes0 = 4 * (size_t)CT * 4096;
  const size_t pBytes1 = (size_t)2 * CM * 1024 * 2;
  const size_t oP    = alloc(pBytes0 > pBytes1 ? pBytes0 : pBytes1);
  const size_t oBFA  = alloc((size_t)CM * 4096);
  const size_t oBFB  = alloc((size_t)CM * 4096);
  const size_t oSel  = alloc((size_t)CM * 16);
  const size_t oSelw = alloc((size_t)CM * 16);
  const size_t oLrow = alloc((size_t)4 * LCAP * 4);
  const size_t oLw   = alloc((size_t)4 * LCAP * 4);
  const size_t oBlk  = alloc((size_t)4 * NBLK * 4);

  _Float16* WHp1 = (_Float16*)(ws + oWHp1); _Float16* WLp1 = (_Float16*)(ws + oWLp1);
  _Float16* WHp2 = (_Float16*)(ws + oWHp2); _Float16* WLp2 = (_Float16*)(ws + oWLp2);
  _Float16* WHm1 = (_Float16*)(ws + oWHm1); _Float16* WLm1 = (_Float16*)(ws + oWLm1);
  _Float16* WHm2 = (_Float16*)(ws + oWHm2); _Float16* WLm2 = (_Float16*)(ws + oWLm2);
  _Float16* WHm3 = (_Float16*)(ws + oWHm3); _Float16* WLm3 = (_Float16*)(ws + oWLm3);
  // MoE weights alias the m-layer split weights (converted AFTER the trunk,
  // re-split at the top of each outer iteration):
  __bf16* WBex = (__bf16*)(ws + oWHm1);   // 16 MB over WHm1+WLm1
  __bf16* WBfu = (__bf16*)(ws + oWHm2);   //  4 MB over WHm2
  _Float16* PH0 = (_Float16*)(ws + oP);
  _Float16* PL0 = (_Float16*)(ws + oP + (size_t)CT * 4096);
  _Float16* PH1 = (_Float16*)(ws + oP + 2 * (size_t)CT * 4096);
  _Float16* PL1 = (_Float16*)(ws + oP + 3 * (size_t)CT * 4096);
  float* F32    = (float*)(ws + oP);      // CT x 2048 f32 (planes 0-1)
  __bf16* ACCb  = (__bf16*)(ws + oP);     // 2*CM x 1024 bf16 (rank-0 partial)
  float* F32fus = (float*)(ws + oP);      // CM x 1024 f32 (fus output)
  __bf16* BFA = (__bf16*)(ws + oBFA);     // LN output bf16, CM x 2048
  __bf16* BFB = (__bf16*)(ws + oBFB);     // moe concat bf16, CM x 2048
  int*   sel  = (int*)(ws + oSel);
  float* selw = (float*)(ws + oSelw);
  int*   lrow = (int*)(ws + oLrow);
  float* lw   = (float*)(ws + oLw);
  int*   blkexp = (int*)(ws + oBlk);
  int*   cnt = (int*)(ws + oCnt);
  int*   cur = (int*)(ws + oCur);
  float* s1v = (float*)(ws + oS1); float* t1v = (float*)(ws + oT1);
  float* s2v = (float*)(ws + oS2); float* t2v = (float*)(ws + oT2);
  float* fsv = (float*)(ws + oFS); float* ftv = (float*)(ws + oFT);

  const dim3 T(256);
  // ---- once: fold BN vectors, p-layer splits (never clobbered) ----
  fold_kernel<<<8, T, 0, stream>>>(bn1_g, bn1_b, m1_b, bn2_g, bn2_b, m2_b,
                                   bnf_g, bnf_b, fus_b, s1v, t1v, s2v, t2v, fsv, ftv);
  split_w<<<1024, T, 0, stream>>>(p1_w, WHp1, WLp1, 1048576);
  split_w<<<1024, T, 0, stream>>>(p2_w, WHp2, WLp2, 1048576);

  const dim3 GP(CT / 128, 8, 2), GT16(CT / 128, 16, 1),
             GM(NBLK, 8, 2), GF(CM / 128, 8);
  for (int m0 = 0; m0 < BROWS; m0 += CM) {
    // m-layer split weights (region shared with WBex/WBfu -> re-split)
    split_w<<<4096, T, 0, stream>>>(m1_w, WHm1, WLm1, 4194304);
    split_w<<<4096, T, 0, stream>>>(m2_w, WHm2, WLm2, 4194304);
    split_w<<<4096, T, 0, stream>>>(m3_w, WHm3, WLm3, 4194304);

    // ---- trunk, inner-chunked at CT ----
    for (int r0 = 0; r0 < CM; r0 += CT) {
      const float* x1c = x1 + (size_t)(m0 + r0) * 1024;
      const float* x2c = x2 + (size_t)(m0 + r0) * 1024;
      prep_x<<<CT, T, 0, stream>>>(x1c, x2c, PH0, PL0);
      // p1 + p2 merged (z selects weight set; A/C offset by 1024 cols)
      gemm_split<0><<<GP, T, 0, stream>>>(PH0, PL0, WHp1, WLp1, WHp2, WLp2,
                                          2048, 1024, 1024,
                                          PH1, PL1, nullptr, 2048,
                                          p1_b, nullptr, p2_b, 1024);
      gemm_split<1><<<GT16, T, 0, stream>>>(PH1, PL1, WHm1, WLm1, WHm1, WLm1,
                                            2048, 2048, 2048,
                                            PH0, PL0, nullptr, 2048,
                                            s1v, t1v, s1v, 0);
      gemm_split<1><<<GT16, T, 0, stream>>>(PH0, PL0, WHm2, WLm2, WHm2, WLm2,
                                            2048, 2048, 2048,
                                            PH1, PL1, nullptr, 2048,
                                            s2v, t2v, s2v, 0);
      gemm_split<2><<<GT16, T, 0, stream>>>(PH1, PL1, WHm3, WLm3, WHm3, WLm3,
                                            2048, 2048, 2048,
                                            nullptr, nullptr, F32, 2048,
                                            m3_b, nullptr, m3_b, 0);
      // LN + fused gate (writes BFA bf16 + sel/selw; no F32 writeback)
      ln_gate_kernel<<<CT, T, 0, stream>>>(F32, BFA + (size_t)r0 * 2048,
                                           ln_g, ln_b, gate_w, gate_b,
                                           sel, selw, r0, CM * 2);
    }

    // ---- MoE weights (clobber m-layer splits now that trunk is done) ----
    cvt_bf<<<8192, T, 0, stream>>>(ex_w, WBex, 8388608);
    cvt_bf<<<2048, T, 0, stream>>>(fus_w, WBfu, 2097152);

    // ---- full-batch MoE (ballot-aggregated bucketing) ----
    hipMemsetAsync(cnt, 0, 32 * 4, stream);
    count_kernel<<<(2 * CM + 255) / 256, T, 0, stream>>>(sel, cnt, CM);
    prefix_kernel<<<1, T, 0, stream>>>(cnt, cur, blkexp, NBLK);
    hipMemsetAsync(lrow, 0xFF, (size_t)4 * LCAP * 4, stream);
    scatter_kernel<<<(2 * CM + 255) / 256, T, 0, stream>>>(sel, selw, cur, lrow, lw, CM, LCAP);
    // rank-0 pass (both halves), then rank-1 pass (both halves)
    gemm_moe<0><<<GM, T, 0, stream>>>(BFA, WBex, lrow, lw, blkexp, ex_b,
                                      ACCb, BFB, CM, LCAP, NBLK, 0);
    gemm_moe<1><<<GM, T, 0, stream>>>(BFA, WBex, lrow, lw, blkexp, ex_b,
                                      ACCb, BFB, CM, LCAP, NBLK, 1);

    // ---- fus + reg on the full outer chunk ----
    gemm_fus<<<GF, T, 0, stream>>>(BFB, WBfu, 2048, 2048, 2048, F32fus, 1024, fsv, ftv);
    reg_kernel<<<CM / 4, T, 0, stream>>>(F32fus, reg_w, reg_b, (float*)d_out + m0);
  }
}